// Round 15
// baseline (938.721 us; speedup 1.0000x reference)
//
#include <hip/hip_runtime.h>

typedef unsigned short u16;
typedef __attribute__((ext_vector_type(8))) short short8;
typedef __attribute__((ext_vector_type(4))) float f4;
typedef __attribute__((ext_vector_type(4))) unsigned short u16x4;

__device__ __forceinline__ float b2f(u16 u) {
    unsigned int x = ((unsigned int)u) << 16;
    return __builtin_bit_cast(float, x);
}
__device__ __forceinline__ u16 f2b(float f) {
    unsigned int u = __builtin_bit_cast(unsigned int, f);
    u += 0x7FFFu + ((u >> 16) & 1u);   // round-to-nearest-even
    return (u16)(u >> 16);
}

__device__ __forceinline__ void gl16(const void* g, void* l) {
    __builtin_amdgcn_global_load_lds(
        (const __attribute__((address_space(1))) void*)g,
        (__attribute__((address_space(3))) void*)l, 16, 0, 0);
}

// ---------------------------------------------------------------------------
// bf16 MFMA GEMM, global_load_lds staging + double-buffered LDS:
//   C[M,N] = A[M,K] @ Bt[N,K]^T  (+bias, +relu)
// Tile (FM*32)x(FN*32), BK=32, 4 waves (2x2).
// CBF: 0 f32-out, 1 bf16-out, 2 bf16 V^T-out,
//      3 z-switch {z=0: bf16->Cp ldc ; z=1: V^T->Cp2 ldc2},
//      4 z-switch {z<2: bf16->Cp+sCh*hh ; z=2: V^T->Cp2 ldc2}.
// EPI: 0 none, 1 +bias, 2 +bias+relu. Multi-source via batch strides.
// ---------------------------------------------------------------------------
template<int FM, int FN, int CBF, int EPI, int LB>
__global__ __launch_bounds__(256, LB)
void gemm_bt(const u16* __restrict__ Ap, const u16* __restrict__ Bp,
             void* __restrict__ Cp, void* __restrict__ Cp2, int ldc2,
             const float* __restrict__ bias,
             int M, int N, int K, int lda, int ldb, int ldc,
             long long sAh, long long sAb, long long sBh, long long sBb,
             long long sCh, long long sCb, int batchH)
{
    constexpr int BM = FM * 32;
    constexpr int BN = FN * 32;
    __shared__ __align__(16) u16 As[2][BM * 32];
    __shared__ __align__(16) u16 Bs[2][BN * 32];

    const int tid  = threadIdx.x;
    const int z    = blockIdx.z;
    const int bb   = z / batchH;
    const int hh   = z - bb * batchH;
    const int m0   = blockIdx.y * BM;
    const int n0   = blockIdx.x * BN;
    const int w    = tid >> 6;
    const int lane = tid & 63;
    const int wr   = w >> 1;
    const int wc   = w & 1;
    const int lrow = lane & 15;
    const int lk   = (lane >> 4) << 3;
    const int lrow4 = lane >> 2;
    const int lch   = lane & 3;

    const u16* Ag = Ap + sAb * bb + sAh * hh;
    const u16* Bg = Bp + sBb * bb + sBh * hh;

    f4 acc[FM][FN] = {};

    auto stage = [&](int buf, int kt) {
        const int kb = kt << 5;
        #pragma unroll
        for (int i = 0; i < BM / 64; ++i) {
            const int row0 = (w + i * 4) << 4;
            gl16(Ag + (long long)(m0 + row0 + lrow4) * lda + kb + (lch << 3),
                 &As[buf][row0 * 32]);
        }
        #pragma unroll
        for (int i = 0; i < BN / 64; ++i) {
            const int row0 = (w + i * 4) << 4;
            gl16(Bg + (long long)(n0 + row0 + lrow4) * ldb + kb + (lch << 3),
                 &Bs[buf][row0 * 32]);
        }
    };

    const int nKt = K >> 5;
    stage(0, 0);
    __syncthreads();
    int cur = 0;
    for (int kt = 0; kt < nKt; ++kt) {
        if (kt + 1 < nKt) stage(cur ^ 1, kt + 1);

        short8 af[FM], bv[FN];
        #pragma unroll
        for (int m = 0; m < FM; ++m)
            af[m] = *(const short8*)(&As[cur][(wr * FM * 16 + m * 16 + lrow) * 32 + lk]);
        #pragma unroll
        for (int n = 0; n < FN; ++n)
            bv[n] = *(const short8*)(&Bs[cur][(wc * FN * 16 + n * 16 + lrow) * 32 + lk]);
        #pragma unroll
        for (int m = 0; m < FM; ++m)
            #pragma unroll
            for (int n = 0; n < FN; ++n)
                acc[m][n] = __builtin_amdgcn_mfma_f32_16x16x32_bf16(af[m], bv[n], acc[m][n], 0, 0, 0);

        __syncthreads();
        cur ^= 1;
    }

    const int crow0 = m0 + wr * FM * 16 + ((lane >> 4) << 2);
    const int ccol0 = n0 + wc * FN * 16 + lrow;
    const bool vtpath = (CBF == 2) || (CBF == 3 && z == 1) || (CBF == 4 && z == 2);
    if (CBF == 0) {
        float* Cg = (float*)Cp + sCb * bb + sCh * hh;
        #pragma unroll
        for (int m = 0; m < FM; ++m) {
            #pragma unroll
            for (int n = 0; n < FN; ++n) {
                const int col = ccol0 + n * 16;
                float bvv = (EPI >= 1) ? bias[col] : 0.f;
                #pragma unroll
                for (int r = 0; r < 4; ++r) {
                    float vv = acc[m][n][r] + bvv;
                    if (EPI == 2) vv = fmaxf(vv, 0.f);
                    Cg[(long long)(crow0 + m * 16 + r) * ldc + col] = vv;
                }
            }
        }
    } else if (!vtpath) {
        u16* Cg = (u16*)Cp + sCb * bb + sCh * hh;
        #pragma unroll
        for (int m = 0; m < FM; ++m) {
            #pragma unroll
            for (int n = 0; n < FN; ++n) {
                const int col = ccol0 + n * 16;
                float bvv = (EPI >= 1) ? bias[col] : 0.f;
                #pragma unroll
                for (int r = 0; r < 4; ++r) {
                    float vv = acc[m][n][r] + bvv;
                    if (EPI == 2) vv = fmaxf(vv, 0.f);
                    Cg[(long long)(crow0 + m * 16 + r) * ldc + col] = f2b(vv);
                }
            }
        }
    } else {
        const int ldv = (CBF == 2) ? ldc : ldc2;
        u16* Cg = (CBF == 2) ? (u16*)Cp : (u16*)Cp2;
        #pragma unroll
        for (int m = 0; m < FM; ++m) {
            const int row0 = crow0 + m * 16;
            const int b2 = row0 / ldv;
            const int j = row0 - b2 * ldv;
            #pragma unroll
            for (int n = 0; n < FN; ++n) {
                const int col = ccol0 + n * 16;
                u16x4 o;
                o.x = f2b(acc[m][n][0]); o.y = f2b(acc[m][n][1]);
                o.z = f2b(acc[m][n][2]); o.w = f2b(acc[m][n][3]);
                *(u16x4*)(Cg + ((long long)(b2 * 1024 + col)) * ldv + j) = o;
            }
        }
    }
}

// ---------------------------------------------------------------------------
// Merged pre-fattn-self GEMMs (all K=1024, lda=ldb=1024, FM=2/FN=4):
//  z=0: K1  = cat @ Wk1^T -> K1b bf16 (ld 1056)          grid (8,128)
//  z=1: V1^T= (cat @ Wv1^T)^T -> vtb (ldv 2048)          grid (8,128)
//  z=2..5: Q1 batch b=z-2 (tgt rows of cat) -> qb1       grid (8,16)
//  z=6: R12 = pos @ [Wr1|Wr2]^T -> R12 (ld 2048)         grid (16,32)
// Out-of-range blocks exit immediately.
// ---------------------------------------------------------------------------
__global__ __launch_bounds__(256, 4)
void gemm_pre1(const u16* __restrict__ cat_bf, const u16* __restrict__ pos_bf,
               const u16* __restrict__ W1t, const u16* __restrict__ Wr12t,
               u16* __restrict__ K1b, u16* __restrict__ vtb,
               u16* __restrict__ qb1, u16* __restrict__ R12)
{
    const int z = blockIdx.z;
    const u16 *Ap, *Bp;
    u16* Cb;
    int ldc, mode, bxmax, bymax;
    if (z < 2) {
        Ap = cat_bf; Bp = W1t + (z + 1) * 1048576;
        bxmax = 8; bymax = 128;
        if (z == 0) { Cb = K1b; ldc = 1056; mode = 0; }
        else        { Cb = vtb; ldc = 2048; mode = 1; }
    } else if (z < 6) {
        Ap = cat_bf + 1048576 + (long long)(z - 2) * 2097152;
        Bp = W1t;
        Cb = qb1 + (long long)(z - 2) * 1048576;
        ldc = 1024; mode = 0; bxmax = 8; bymax = 16;
    } else {
        Ap = pos_bf; Bp = Wr12t; Cb = R12;
        ldc = 2048; mode = 0; bxmax = 16; bymax = 32;
    }
    if ((int)blockIdx.x >= bxmax || (int)blockIdx.y >= bymax) return;

    constexpr int BM = 64, BN = 128;
    __shared__ __align__(16) u16 As[2][BM * 32];
    __shared__ __align__(16) u16 Bs[2][BN * 32];

    const int tid  = threadIdx.x;
    const int m0   = blockIdx.y * BM;
    const int n0   = blockIdx.x * BN;
    const int w    = tid >> 6;
    const int lane = tid & 63;
    const int wr   = w >> 1;
    const int wc   = w & 1;
    const int lrow = lane & 15;
    const int lk   = (lane >> 4) << 3;
    const int lrow4 = lane >> 2;
    const int lch   = lane & 3;

    f4 acc[2][4] = {};

    auto stage = [&](int buf, int kt) {
        const int kb = kt << 5;
        {
            const int row0 = w << 4;
            gl16(Ap + (long long)(m0 + row0 + lrow4) * 1024 + kb + (lch << 3),
                 &As[buf][row0 * 32]);
        }
        #pragma unroll
        for (int i = 0; i < 2; ++i) {
            const int row0 = (w + i * 4) << 4;
            gl16(Bp + (long long)(n0 + row0 + lrow4) * 1024 + kb + (lch << 3),
                 &Bs[buf][row0 * 32]);
        }
    };

    stage(0, 0);
    __syncthreads();
    int cur = 0;
    for (int kt = 0; kt < 32; ++kt) {
        if (kt + 1 < 32) stage(cur ^ 1, kt + 1);
        short8 af[2], bv[4];
        #pragma unroll
        for (int m = 0; m < 2; ++m)
            af[m] = *(const short8*)(&As[cur][(wr * 32 + m * 16 + lrow) * 32 + lk]);
        #pragma unroll
        for (int n = 0; n < 4; ++n)
            bv[n] = *(const short8*)(&Bs[cur][(wc * 64 + n * 16 + lrow) * 32 + lk]);
        #pragma unroll
        for (int m = 0; m < 2; ++m)
            #pragma unroll
            for (int n = 0; n < 4; ++n)
                acc[m][n] = __builtin_amdgcn_mfma_f32_16x16x32_bf16(af[m], bv[n], acc[m][n], 0, 0, 0);
        __syncthreads();
        cur ^= 1;
    }

    const int crow0 = m0 + wr * 32 + ((lane >> 4) << 2);
    const int ccol0 = n0 + wc * 64 + lrow;
    if (mode == 0) {
        #pragma unroll
        for (int m = 0; m < 2; ++m) {
            #pragma unroll
            for (int n = 0; n < 4; ++n) {
                const int col = ccol0 + n * 16;
                #pragma unroll
                for (int r = 0; r < 4; ++r)
                    Cb[(long long)(crow0 + m * 16 + r) * ldc + col] = f2b(acc[m][n][r]);
            }
        }
    } else {
        // V^T: vt[(b*1024+col)*2048 + j], b = row/2048, j = row%2048
        #pragma unroll
        for (int m = 0; m < 2; ++m) {
            const int row0 = crow0 + m * 16;
            const int b2 = row0 >> 11;
            const int j = row0 & 2047;
            #pragma unroll
            for (int n = 0; n < 4; ++n) {
                const int col = ccol0 + n * 16;
                u16x4 o;
                o.x = f2b(acc[m][n][0]); o.y = f2b(acc[m][n][1]);
                o.z = f2b(acc[m][n][2]); o.w = f2b(acc[m][n][3]);
                *(u16x4*)(Cb + ((long long)(b2 * 1024 + col)) * 2048 + j) = o;
            }
        }
    }
}

// ---------------------------------------------------------------------------
// Fused attention v8: swapped-operand + wave-interleaved + XCD-swizzled grid
// + software-pipelined K gathers + setprio around MFMA clusters.
// 16 q-rows, 512 threads (8 waves), 1D grid 4096 (bijective XCD chunking).
// MODE 0: self causal (limit=t+1024), KK=2048. MODE 1: cross, KK=1024.
// ---------------------------------------------------------------------------
template<int KK, int MODE>
__global__ __launch_bounds__(512, 4)
void fattn(const u16* __restrict__ qsrc, long long qld, long long qsb,
           const float* __restrict__ rwb, const float* __restrict__ rrb,
           const u16* __restrict__ kb, const u16* __restrict__ rr,
           const u16* __restrict__ vt,
           float* __restrict__ probs, u16* __restrict__ ob, int kld)
{
    constexpr int LE = KK + 8;
    constexpr int NT = KK / 16;
    constexpr int NI = NT / 8;
    constexpr int NB = NI / 4;
    __shared__ __align__(16) u16 e[16 * LE];
    __shared__ __align__(16) u16 qws[16 * 72];
    __shared__ __align__(16) u16 qrs[17 * 72];
    __shared__ float psum[8][16];

    const int tid = threadIdx.x;
    const int bid = blockIdx.x;
    const int nid = ((bid & 7) << 9) + (bid >> 3);
    const int bh  = nid >> 6;
    const int t0  = (nid & 63) << 4;
    const int b   = bh >> 4, h = bh & 15;

    if (tid < 264) {
        int row, ch; const float* bias; u16* dst; bool act = true;
        if (tid < 128)      { row = tid >> 3;        ch = tid & 7; bias = rwb; dst = &qws[row * 72 + ch * 8]; }
        else if (tid < 256) { row = (tid - 128) >> 3; ch = tid & 7; bias = rrb; dst = &qrs[row * 72 + ch * 8]; }
        else if (MODE == 1) { row = 16;              ch = tid - 256; bias = rrb; dst = &qrs[16 * 72 + ch * 8]; }
        else act = false;
        if (act) {
            int trow = t0 + row; if (trow > 1023) trow = 1023;
            short8 qv = *(const short8*)(qsrc + b * qsb + (long long)trow * qld + h * 64 + ch * 8);
            const float* bp = bias + h * 64 + ch * 8;
            f4 b0 = *(const f4*)bp, b1 = *(const f4*)(bp + 4);
            short8 o;
            o[0] = (short)f2b((b2f((u16)qv[0]) + b0.x) * 0.125f);
            o[1] = (short)f2b((b2f((u16)qv[1]) + b0.y) * 0.125f);
            o[2] = (short)f2b((b2f((u16)qv[2]) + b0.z) * 0.125f);
            o[3] = (short)f2b((b2f((u16)qv[3]) + b0.w) * 0.125f);
            o[4] = (short)f2b((b2f((u16)qv[4]) + b1.x) * 0.125f);
            o[5] = (short)f2b((b2f((u16)qv[5]) + b1.y) * 0.125f);
            o[6] = (short)f2b((b2f((u16)qv[6]) + b1.z) * 0.125f);
            o[7] = (short)f2b((b2f((u16)qv[7]) + b1.w) * 0.125f);
            *(short8*)dst = o;
        }
    }
    __syncthreads();

    const int w = tid >> 6, lane = tid & 63;
    const int lc = lane & 15, g = lane >> 4, lk = g << 3;
    const int t = t0 + lc;

    const short8 bq0 = *(const short8*)&qws[lc * 72 + lk];
    const short8 bq1 = *(const short8*)&qws[lc * 72 + 32 + lk];
    const short8 br0 = *(const short8*)&qrs[lc * 72 + lk];
    const short8 br1 = *(const short8*)&qrs[lc * 72 + 32 + lk];
    short8 bs0 = {}, bs1 = {};
    if (MODE == 1) {
        bs0 = *(const short8*)&qrs[(lc + 1) * 72 + lk];
        bs1 = *(const short8*)&qrs[(lc + 1) * 72 + 32 + lk];
    }

    // ---- A0: BD~ pre-shifted write-only; 2-deep batched R-gathers
    #pragma unroll
    for (int Bb = 0; Bb < NI; Bb += 2) {
        short8 R0[2], R1[2];
        #pragma unroll
        for (int u = 0; u < 2; ++u) {
            const int ut = w + (Bb + u) * 8;
            const int u0 = ut << 4;
            const bool nd = (u0 + t0 + 30 >= 1023) || (MODE == 1 && u0 + t0 <= 1021);
            if (nd) {
                const u16* rg = rr + (long long)(u0 + lc) * 2048 + h * 64;
                R0[u] = *(const short8*)(rg + lk);
                R1[u] = *(const short8*)(rg + 32 + lk);
            }
        }
        #pragma unroll
        for (int u = 0; u < 2; ++u) {
            const int ut = w + (Bb + u) * 8;
            const int u0 = ut << 4;
            const bool need1 = (u0 + t0 + 30 >= 1023);
            const bool need2 = (MODE == 1) && (u0 + t0 <= 1021);
            if (need1) {
                f4 acc = {};
                acc = __builtin_amdgcn_mfma_f32_16x16x32_bf16(R0[u], br0, acc, 0, 0, 0);
                acc = __builtin_amdgcn_mfma_f32_16x16x32_bf16(R1[u], br1, acc, 0, 0, 0);
                #pragma unroll
                for (int i = 0; i < 4; ++i) {
                    const int j = u0 + 4 * g + i + t - 1023;
                    if (j >= 0) e[lc * LE + j] = f2b(acc[i]);
                }
            }
            if (MODE == 1 && need2) {
                f4 acc = {};
                acc = __builtin_amdgcn_mfma_f32_16x16x32_bf16(R0[u], bs0, acc, 0, 0, 0);
                acc = __builtin_amdgcn_mfma_f32_16x16x32_bf16(R1[u], bs1, acc, 0, 0, 0);
                #pragma unroll
                for (int i = 0; i < 4; ++i) {
                    const int j = u0 + 4 * g + i + t + 2;
                    if (j < KK) e[lc * LE + j] = f2b(acc[i]);
                }
            }
        }
    }
    __syncthreads();

    // ---- A1: AC + BD-add + exp + row-sum; pipelined 4-deep batched K-gathers
    float sum = 0.f;
    const int limit = t + 1024;
    const int jvt = (MODE == 0) ? ((t0 + 1039) >> 4) : (NT - 1);
    {
        short8 K0a[4], K0b[4], K1c[4];
        auto ldK0 = [&](short8* dst, int B2) {
            #pragma unroll
            for (int u = 0; u < 4; ++u) {
                const int jt = w + (B2 * 4 + u) * 8;
                if (MODE != 0 || jt <= jvt) {
                    const u16* kg = kb + (long long)(b * KK + (jt << 4) + lc) * kld + h * 64;
                    dst[u] = *(const short8*)(kg + lk);
                }
            }
        };
        ldK0(K0a, 0);
        #pragma unroll
        for (int B2 = 0; B2 < NB; ++B2) {
            short8* K0c = (B2 & 1) ? K0b : K0a;
            short8* K0n = (B2 & 1) ? K0a : K0b;
            #pragma unroll
            for (int u = 0; u < 4; ++u) {
                const int jt = w + (B2 * 4 + u) * 8;
                if (MODE != 0 || jt <= jvt) {
                    const u16* kg = kb + (long long)(b * KK + (jt << 4) + lc) * kld + h * 64;
                    K1c[u] = *(const short8*)(kg + 32 + lk);
                }
            }
            if (B2 + 1 < NB) ldK0(K0n, B2 + 1);
            __builtin_amdgcn_s_setprio(1);
            #pragma unroll
            for (int u = 0; u < 4; ++u) {
                const int jt = w + (B2 * 4 + u) * 8;
                const int jme = (jt << 4) + 4 * g;
                if (MODE == 0 && jt > jvt) {
                    u16x4 zz = {0, 0, 0, 0};
                    *(u16x4*)&e[lc * LE + jme] = zz;
                } else {
                    f4 acc = {};
                    acc = __builtin_amdgcn_mfma_f32_16x16x32_bf16(K0c[u], bq0, acc, 0, 0, 0);
                    acc = __builtin_amdgcn_mfma_f32_16x16x32_bf16(K1c[u], bq1, acc, 0, 0, 0);
                    u16x4 bd4 = *(const u16x4*)&e[lc * LE + jme];
                    u16x4 st;
                    #pragma unroll
                    for (int i = 0; i < 4; ++i) {
                        const int j = jme + i;
                        float bd = b2f(bd4[i]);
                        if (MODE == 1 && j == t + 1) bd = 0.f;
                        float ev = __expf(acc[i] + bd);
                        if (MODE == 0 && j > limit) ev = 0.f;
                        sum += ev;
                        st[i] = f2b(ev);
                    }
                    *(u16x4*)&e[lc * LE + jme] = st;
                }
            }
            __builtin_amdgcn_s_setprio(0);
        }
    }
    sum += __shfl_xor(sum, 16);
    sum += __shfl_xor(sum, 32);
    if (g == 0) psum[w][lc] = sum;
    __syncthreads();

    if (w >= 4) {
        const int r = (tid >> 4) & 15;
        const int q = tid & 15;
        float s = 0.f;
        #pragma unroll
        for (int w2 = 0; w2 < 8; ++w2) s += psum[w2][r];
        const float inv = 1.f / s;
        float* pr = probs + ((long long)bh * 1024 + t0 + r) * KK;
        #pragma unroll 4
        for (int i2 = 0; i2 < KK / 128; ++i2) {
            const int j0 = q * 8 + i2 * 128;
            u16x4 e0 = *(const u16x4*)&e[r * LE + j0];
            u16x4 e1 = *(const u16x4*)&e[r * LE + j0 + 4];
            f4 p0, p1;
            p0.x = b2f(e0.x) * inv; p0.y = b2f(e0.y) * inv;
            p0.z = b2f(e0.z) * inv; p0.w = b2f(e0.w) * inv;
            p1.x = b2f(e1.x) * inv; p1.y = b2f(e1.y) * inv;
            p1.z = b2f(e1.z) * inv; p1.w = b2f(e1.w) * inv;
            __builtin_nontemporal_store(p0, (f4*)(pr + j0));
            __builtin_nontemporal_store(p1, (f4*)(pr + j0 + 4));
        }
    } else {
        const int db = w << 4;
        const u16* vrow = vt + ((long long)(bh * 64 + db + lc)) * KK + lk;
        int kcend = KK / 32;
        if (MODE == 0) {
            const int ke = (t0 + 1071) >> 5;
            if (ke < kcend) kcend = ke;
        }
        f4 acc = {};
        __builtin_amdgcn_s_setprio(1);
        #pragma unroll 2
        for (int kc = 0; kc < kcend; ++kc) {
            short8 a = *(const short8*)&e[lc * LE + kc * 32 + lk];
            short8 bv = *(const short8*)(vrow + kc * 32);
            acc = __builtin_amdgcn_mfma_f32_16x16x32_bf16(a, bv, acc, 0, 0, 0);
        }
        __builtin_amdgcn_s_setprio(0);
        #pragma unroll
        for (int i = 0; i < 4; ++i) {
            const int trow = g * 4 + i;
            float s = 0.f;
            #pragma unroll
            for (int w2 = 0; w2 < 8; ++w2) s += psum[w2][trow];
            ob[((long long)(b * 1024 + t0 + trow)) * 1024 + h * 64 + db + lc] = f2b(acc[i] / s);
        }
    }
}

// ---------------------------------------------------------------------------
__global__ void prep0(const float* __restrict__ mem, const float* __restrict__ tgt,
                      const float* __restrict__ src, const float* __restrict__ pos,
                      float* __restrict__ nm, u16* __restrict__ cat,
                      u16* __restrict__ srcb, u16* __restrict__ posb)
{
    const int bid = blockIdx.x;
    const int tid = threadIdx.x;
    if (bid < 8192) {
        long long i = (long long)bid * 256 + tid;
        long long b = i >> 19;
        int rem = (int)(i & 524287);
        int r = rem >> 8, c4 = rem & 255;
        const float* sp = (r < 1024) ? (mem + ((b << 10) + r) * 1024 + c4 * 4)
                                     : (tgt + ((b << 10) + (r - 1024)) * 1024 + c4 * 4);
        f4 v = *(const f4*)sp;
        __builtin_nontemporal_store(v, (f4*)(nm + i * 4));
        u16x4 o; o.x = f2b(v.x); o.y = f2b(v.y); o.z = f2b(v.z); o.w = f2b(v.w);
        *(u16x4*)(cat + i * 4) = o;
    } else if (bid < 12288) {
        long long i = (long long)(bid - 8192) * 256 + tid;
        f4 v = *(const f4*)(src + i * 4);
        u16x4 o; o.x = f2b(v.x); o.y = f2b(v.y); o.z = f2b(v.z); o.w = f2b(v.w);
        *(u16x4*)(srcb + i * 4) = o;
    } else {
        long long i = (long long)(bid - 12288) * 256 + tid;
        f4 v = *(const f4*)(pos + i * 4);
        u16x4 o; o.x = f2b(v.x); o.y = f2b(v.y); o.z = f2b(v.z); o.w = f2b(v.w);
        *(u16x4*)(posb + i * 4) = o;
    }
}

struct TWS { const float* s; u16* d; int sld, dld; };
struct TW18 { TWS t[18]; };
__global__ void transpose_w18(TW18 p)
{
    __shared__ float tile[32][33];
    const TWS ts = p.t[blockIdx.z];
    int c0 = blockIdx.x * 32, r0 = blockIdx.y * 32;
    int tx = threadIdx.x, ty = threadIdx.y;
    tile[ty][tx] = ts.s[(long long)(r0 + ty) * ts.sld + c0 + tx];
    __syncthreads();
    ts.d[(long long)(c0 + ty) * ts.dld + r0 + tx] = f2b(tile[tx][ty]);
}

// out = LN(x + h1 + h2? + hbias?) * g + bl ; obf==nullptr -> NT final store.
__global__ __launch_bounds__(256) void ln_res(const float* __restrict__ x,
                                              const float* __restrict__ h1,
                                              const float* __restrict__ h2,
                                              const float* __restrict__ hbias,
                                              const float* __restrict__ g, const float* __restrict__ bl,
                                              float* __restrict__ o32, u16* __restrict__ obf)
{
    const long long row = blockIdx.x;
    const int tid = threadIdx.x;
    const long long base = row * 1024 + tid * 4;
    f4 xa = *(const f4*)(x + base);
    f4 ha = *(const f4*)(h1 + base);
    f4 hb = {0.f, 0.f, 0.f, 0.f};
    if (h2) hb = *(const f4*)(h2 + base);
    f4 hc = {0.f, 0.f, 0.f, 0.f};
    if (hbias) hc = *(const f4*)(hbias + tid * 4);
    float v0 = xa.x + ha.x + hb.x + hc.x, v1 = xa.y + ha.y + hb.y + hc.y;
    float v2 = xa.z + ha.z + hb.z + hc.z, v3 = xa.w + ha.w + hb.w + hc.w;
    float lsum = v0 + v1 + v2 + v3;
    float lsq = v0 * v0 + v1 * v1 + v2 * v2 + v3 * v3;
    #pragma unroll
    for (int o2 = 32; o2; o2 >>= 1) { lsum += __shfl_xor(lsum, o2); lsq += __shfl_xor(lsq, o2); }
    __shared__ float r1[4], r2[4];
    int w = tid >> 6, lane = tid & 63;
    if (lane == 0) { r1[w] = lsum; r2[w] = lsq; }
    __syncthreads();
    lsum = r1[0] + r1[1] + r1[2] + r1[3];
    lsq  = r2[0] + r2[1] + r2[2] + r2[3];
    const float mu = lsum * 0.0009765625f;
    const float var = lsq * 0.0009765625f - mu * mu;
    const float rsd = rsqrtf(var + 1e-5f);
    const int c = tid * 4;
    f4 gv = *(const f4*)(g + c);
    f4 bv = *(const f4*)(bl + c);
    f4 y;
    y.x = (v0 - mu) * rsd * gv.x + bv.x;
    y.y = (v1 - mu) * rsd * gv.y + bv.y;
    y.z = (v2 - mu) * rsd * gv.z + bv.z;
    y.w = (v3 - mu) * rsd * gv.w + bv.w;
    if (obf) {
        *(f4*)(o32 + base) = y;
        u16x4 u; u.x = f2b(y.x); u.y = f2b(y.y); u.z = f2b(y.z); u.w = f2b(y.w);
        *(u16x4*)(obf + base) = u;
    } else {
        __builtin_nontemporal_store(y, (f4*)(o32 + base));
    }
}

// ---------------------------------------------------------------------------
extern "C" void kernel_launch(void* const* d_in, const int* in_sizes, int n_in,
                              void* d_out, int out_size, void* d_ws, size_t ws_size,
                              hipStream_t stream)
{
    (void)in_sizes; (void)n_in; (void)out_size;
    const float* src  = (const float*)d_in[0];
    const float* tgt  = (const float*)d_in[1];
    const float* mem  = (const float*)d_in[2];
    const float* pos  = (const float*)d_in[3];
    const float* rwb  = (const float*)d_in[4];
    const float* rrb  = (const float*)d_in[5];
    const float* Wq1  = (const float*)d_in[6];
    const float* Wk1  = (const float*)d_in[7];
    const float* Wv1  = (const float*)d_in[8];
    const float* Wr1  = (const float*)d_in[9];
    const float* Wo1  = (const float*)d_in[10];
    const float* ln1g = (const float*)d_in[11];
    const float* ln1b = (const float*)d_in[12];
    const float* Wq2  = (const float*)d_in[13];
    const float* Wk2  = (const float*)d_in[14];
    const float* Wv2  = (const float*)d_in[15];
    const float* Wr2  = (const float*)d_in[16];
    const float* Wo2  = (const float*)d_in[17];
    const float* ln2g = (const float*)d_in[18];
    const float* ln2b = (const float*)d_in[19];
    const float* Wf1  = (const float*)d_in[20];
    const float* bf1  = (const float*)d_in[21];
    const float* Wf2  = (const float*)d_in[22];
    const float* bf2  = (const float*)d_in[23];
    const float* ln3g = (const float*)d_in[24];
    const float* ln3b = (const float*)d_in[25];

    float* outp   = (float*)d_out;            // [4,1024,1024]
    float* newmem = outp + 4194304;           // [4,2048,1024]
    float* selfP  = outp + 12582912;          // [4,16,1024,2048]
    float* interP = outp + 146800640;         // [4,16,1024,1024]

    char* ws = (char*)d_ws;
    size_t off = 0;
    auto alloc = [&](size_t bytes) -> void* {
        void* p = ws + off;
        off = (off + bytes + 255) & ~(size_t)255;
        return p;
    };
    u16*   src_bf  = (u16*)alloc(8u << 20);
    u16*   cat_bf  = (u16*)alloc(16u << 20);
    u16*   pos_bf  = (u16*)alloc(4u << 20);
    u16*   W1t    = (u16*)alloc(6u << 20);
    u16*   Wr12t  = (u16*)alloc(4u << 20);
    u16*   W2t    = (u16*)alloc(4u << 20);
    u16*   Wq2t   = (u16*)alloc(2u << 20);
    u16*   Wo1t   = (u16*)alloc(2u << 20);
    u16*   Wo2t   = (u16*)alloc(2u << 20);
    u16*   Wf1t   = (u16*)alloc(8u << 20);
    u16*   Wf2t   = (u16*)alloc(8u << 20);
    u16*   K1b    = (u16*)alloc(18u << 20);
    u16*   qb1    = (u16*)alloc(8u << 20);
    u16*   P2k    = (u16*)alloc(8u << 20);
    u16*   R12    = (u16*)alloc(8u << 20);
    u16*   qb2    = (u16*)alloc(8u << 20);
    u16*   vtb    = (u16*)alloc(16u << 20);
    u16*   ob     = (u16*)alloc(8u << 20);
    float* projb  = (float*)alloc(16u << 20);
    float* out1_32 = (float*)alloc(16u << 20);
    u16*   out1_bf = (u16*)alloc(8u << 20);
    float* out2_32 = (float*)alloc(16u << 20);
    u16*   out2_bf = (u16*)alloc(8u << 20);
    u16*   hb     = (u16*)alloc(32u << 20);
    if (off > ws_size) return;

    dim3 tb(32, 32);

    // ---- phase 0
    prep0<<<14336, 256, 0, stream>>>(mem, tgt, src, pos, newmem, cat_bf, src_bf, pos_bf);
    TW18 tw;
    tw.t[0] = {Wq1, W1t, 1024, 1024};
    tw.t[1] = {Wk1, W1t + 1048576, 1024, 1024};
    tw.t[2] = {Wv1, W1t + 2097152, 1024, 1024};
    tw.t[3] = {Wr1, Wr12t, 1024, 1024};
    tw.t[4] = {Wr2, Wr12t + 1048576, 1024, 1024};
    tw.t[5] = {Wk2, W2t, 1024, 1024};
    tw.t[6] = {Wv2, W2t + 1048576, 1024, 1024};
    tw.t[7] = {Wq2, Wq2t, 1024, 1024};
    tw.t[8] = {Wo1, Wo1t, 1024, 1024};
    tw.t[9] = {Wo2, Wo2t, 1024, 1024};
    for (int zz = 0; zz < 4; ++zz) {
        tw.t[10 + zz] = {Wf1 + zz * 1024, Wf1t + (long long)zz * 1048576, 4096, 1024};
        tw.t[14 + zz] = {Wf2 + (long long)zz * 1048576, Wf2t + zz * 1024, 1024, 4096};
    }
    transpose_w18<<<dim3(32, 32, 18), tb, 0, stream>>>(tw);

    // ---- layer 1: self relative attention (K=2048)
    // One launch: K1 + V1^T + Q1(x4) + R12
    gemm_pre1<<<dim3(16, 128, 7), 256, 0, stream>>>(cat_bf, pos_bf, W1t, Wr12t,
                                                    K1b, vtb, qb1, R12);
    fattn<2048,0><<<4096, 512, 0, stream>>>(qb1, 1024LL, 1048576LL,
        rwb, rrb, K1b, R12, vtb, selfP, ob, 1056);
    gemm_bt<2,4,0,0,4><<<dim3(8,64,1), 256, 0, stream>>>(ob, Wo1t, projb, nullptr, 0,
        nullptr, 4096,1024,1024, 1024,1024,1024, 0,0,0,0,0,0, 1);
    ln_res<<<4096, 256, 0, stream>>>(tgt, projb, nullptr, nullptr, ln1g, ln1b, out1_32, out1_bf);

    // ---- layer 2: cross relative attention (K=1024)
    {
        // Merged Q2/K2/V2^T: z=0: out1@Wq2 -> qb2; z=1: src@Wk2 -> P2k;
        // z=2: src@Wv2 -> vtb (V^T, ld 1024)
        const long long dA = (long long)(src_bf - out1_bf);
        const long long dB = (long long)(W2t - Wq2t);
        const long long dB2 = (long long)((W2t + 1048576) - Wq2t);
        const long long dC = (long long)(P2k - qb2);
        gemm_bt<2,4,4,0,4><<<dim3(8,64,3), 256, 0, stream>>>(out1_bf, Wq2t, qb2, vtb, 1024,
            nullptr, 4096,1024,1024, 1024,1024,1024, dA,dA, dB,dB2, dC,0, 2);
    }
    fattn<1024,1><<<4096, 512, 0, stream>>>(qb2, 1024LL, 1048576LL,
        rwb, rrb, P2k, R12 + 1024LL * 2048 + 1024, vtb, interP, ob, 1024);
    gemm_bt<2,4,0,0,4><<<dim3(8,64,1), 256, 0, stream>>>(ob, Wo2t, projb, nullptr, 0,
        nullptr, 4096,1024,1024, 1024,1024,1024, 0,0,0,0,0,0, 1);
    ln_res<<<4096, 256, 0, stream>>>(out1_32, projb, nullptr, nullptr, ln2g, ln2b, out2_32, out2_bf);

    // ---- layer 3: FF
    gemm_bt<4,4,1,2,3><<<dim3(32,32,1), 256, 0, stream>>>(out2_bf, Wf1t, hb, nullptr, 0,
        bf1, 4096,4096,1024, 1024,1024,4096, 0,0,0,0,0,0, 1);
    gemm_bt<2,4,0,0,4><<<dim3(8,64,1), 256, 0, stream>>>(hb, Wf2t, projb, nullptr, 0,
        nullptr, 4096,1024,4096, 4096,4096,1024, 0,0,0,0,0,0, 1);
    ln_res<<<4096, 256, 0, stream>>>(out2_32, projb, nullptr, bf2, ln3g, ln3b, outp, nullptr);
}

// Round 16
// 876.935 us; speedup vs baseline: 1.0705x; 1.0705x over previous
//
#include <hip/hip_runtime.h>

typedef unsigned short u16;
typedef __attribute__((ext_vector_type(8))) short short8;
typedef __attribute__((ext_vector_type(4))) float f4;
typedef __attribute__((ext_vector_type(4))) unsigned short u16x4;

__device__ __forceinline__ float b2f(u16 u) {
    unsigned int x = ((unsigned int)u) << 16;
    return __builtin_bit_cast(float, x);
}
__device__ __forceinline__ u16 f2b(float f) {
    unsigned int u = __builtin_bit_cast(unsigned int, f);
    u += 0x7FFFu + ((u >> 16) & 1u);   // round-to-nearest-even
    return (u16)(u >> 16);
}

__device__ __forceinline__ void gl16(const void* g, void* l) {
    __builtin_amdgcn_global_load_lds(
        (const __attribute__((address_space(1))) void*)g,
        (__attribute__((address_space(3))) void*)l, 16, 0, 0);
}

// ---------------------------------------------------------------------------
// bf16 MFMA GEMM, global_load_lds staging + double-buffered LDS:
//   C[M,N] = A[M,K] @ Bt[N,K]^T  (+bias, +relu)
// Tile (FM*32)x(FN*32), BK=32, 4 waves (2x2).
// CBF: 0 f32-out, 1 bf16-out, 2 bf16 V^T-out,
//      3 z-switch {z=0: bf16->Cp ldc ; z=1: V^T->Cp2 ldc2},
//      4 z-switch {z<2: bf16->Cp+sCh*hh ; z=2: V^T->Cp2 ldc2}.
// EPI: 0 none, 1 +bias, 2 +bias+relu. Multi-source via batch strides.
// ---------------------------------------------------------------------------
template<int FM, int FN, int CBF, int EPI>
__global__ __launch_bounds__(256, 3)
void gemm_bt(const u16* __restrict__ Ap, const u16* __restrict__ Bp,
             void* __restrict__ Cp, void* __restrict__ Cp2, int ldc2,
             const float* __restrict__ bias,
             int M, int N, int K, int lda, int ldb, int ldc,
             long long sAh, long long sAb, long long sBh, long long sBb,
             long long sCh, long long sCb, int batchH)
{
    constexpr int BM = FM * 32;
    constexpr int BN = FN * 32;
    __shared__ __align__(16) u16 As[2][BM * 32];
    __shared__ __align__(16) u16 Bs[2][BN * 32];

    const int tid  = threadIdx.x;
    const int z    = blockIdx.z;
    const int bb   = z / batchH;
    const int hh   = z - bb * batchH;
    const int m0   = blockIdx.y * BM;
    const int n0   = blockIdx.x * BN;
    const int w    = tid >> 6;
    const int lane = tid & 63;
    const int wr   = w >> 1;
    const int wc   = w & 1;
    const int lrow = lane & 15;
    const int lk   = (lane >> 4) << 3;
    const int lrow4 = lane >> 2;
    const int lch   = lane & 3;

    const u16* Ag = Ap + sAb * bb + sAh * hh;
    const u16* Bg = Bp + sBb * bb + sBh * hh;

    f4 acc[FM][FN] = {};

    auto stage = [&](int buf, int kt) {
        const int kb = kt << 5;
        #pragma unroll
        for (int i = 0; i < BM / 64; ++i) {
            const int row0 = (w + i * 4) << 4;
            gl16(Ag + (long long)(m0 + row0 + lrow4) * lda + kb + (lch << 3),
                 &As[buf][row0 * 32]);
        }
        #pragma unroll
        for (int i = 0; i < BN / 64; ++i) {
            const int row0 = (w + i * 4) << 4;
            gl16(Bg + (long long)(n0 + row0 + lrow4) * ldb + kb + (lch << 3),
                 &Bs[buf][row0 * 32]);
        }
    };

    const int nKt = K >> 5;
    stage(0, 0);
    __syncthreads();
    int cur = 0;
    for (int kt = 0; kt < nKt; ++kt) {
        if (kt + 1 < nKt) stage(cur ^ 1, kt + 1);

        short8 af[FM], bv[FN];
        #pragma unroll
        for (int m = 0; m < FM; ++m)
            af[m] = *(const short8*)(&As[cur][(wr * FM * 16 + m * 16 + lrow) * 32 + lk]);
        #pragma unroll
        for (int n = 0; n < FN; ++n)
            bv[n] = *(const short8*)(&Bs[cur][(wc * FN * 16 + n * 16 + lrow) * 32 + lk]);
        #pragma unroll
        for (int m = 0; m < FM; ++m)
            #pragma unroll
            for (int n = 0; n < FN; ++n)
                acc[m][n] = __builtin_amdgcn_mfma_f32_16x16x32_bf16(af[m], bv[n], acc[m][n], 0, 0, 0);

        __syncthreads();
        cur ^= 1;
    }

    const int crow0 = m0 + wr * FM * 16 + ((lane >> 4) << 2);
    const int ccol0 = n0 + wc * FN * 16 + lrow;
    const bool vtpath = (CBF == 2) || (CBF == 3 && z == 1) || (CBF == 4 && z == 2);
    if (CBF == 0) {
        float* Cg = (float*)Cp + sCb * bb + sCh * hh;
        #pragma unroll
        for (int m = 0; m < FM; ++m) {
            #pragma unroll
            for (int n = 0; n < FN; ++n) {
                const int col = ccol0 + n * 16;
                float bvv = (EPI >= 1) ? bias[col] : 0.f;
                #pragma unroll
                for (int r = 0; r < 4; ++r) {
                    float vv = acc[m][n][r] + bvv;
                    if (EPI == 2) vv = fmaxf(vv, 0.f);
                    Cg[(long long)(crow0 + m * 16 + r) * ldc + col] = vv;
                }
            }
        }
    } else if (!vtpath) {
        u16* Cg = (u16*)Cp + sCb * bb + sCh * hh;
        #pragma unroll
        for (int m = 0; m < FM; ++m) {
            #pragma unroll
            for (int n = 0; n < FN; ++n) {
                const int col = ccol0 + n * 16;
                float bvv = (EPI >= 1) ? bias[col] : 0.f;
                #pragma unroll
                for (int r = 0; r < 4; ++r) {
                    float vv = acc[m][n][r] + bvv;
                    if (EPI == 2) vv = fmaxf(vv, 0.f);
                    Cg[(long long)(crow0 + m * 16 + r) * ldc + col] = f2b(vv);
                }
            }
        }
    } else {
        // V^T write: vt[(b*1024 + col)*ldv + j], b = row/ldv, j = row%ldv.
        const int ldv = (CBF == 2) ? ldc : ldc2;
        u16* Cg = (CBF == 2) ? (u16*)Cp : (u16*)Cp2;
        #pragma unroll
        for (int m = 0; m < FM; ++m) {
            const int row0 = crow0 + m * 16;
            const int b2 = row0 / ldv;
            const int j = row0 - b2 * ldv;
            #pragma unroll
            for (int n = 0; n < FN; ++n) {
                const int col = ccol0 + n * 16;
                u16x4 o;
                o.x = f2b(acc[m][n][0]); o.y = f2b(acc[m][n][1]);
                o.z = f2b(acc[m][n][2]); o.w = f2b(acc[m][n][3]);
                *(u16x4*)(Cg + ((long long)(b2 * 1024 + col)) * ldv + j) = o;
            }
        }
    }
}

// ---------------------------------------------------------------------------
// Fused attention v8: swapped-operand + wave-interleaved + XCD-swizzled grid
// + software-pipelined K gathers + setprio around MFMA clusters.
// 16 q-rows, 512 threads (8 waves), 1D grid 4096 (bijective XCD chunking).
// MODE 0: self causal (limit=t+1024), KK=2048. MODE 1: cross, KK=1024.
// ---------------------------------------------------------------------------
template<int KK, int MODE>
__global__ __launch_bounds__(512, 4)
void fattn(const u16* __restrict__ qsrc, long long qld, long long qsb,
           const float* __restrict__ rwb, const float* __restrict__ rrb,
           const u16* __restrict__ kb, const u16* __restrict__ rr,
           const u16* __restrict__ vt,
           float* __restrict__ probs, u16* __restrict__ ob, int kld)
{
    constexpr int LE = KK + 8;
    constexpr int NT = KK / 16;
    constexpr int NI = NT / 8;
    constexpr int NB = NI / 4;
    __shared__ __align__(16) u16 e[16 * LE];
    __shared__ __align__(16) u16 qws[16 * 72];
    __shared__ __align__(16) u16 qrs[17 * 72];
    __shared__ float psum[8][16];

    const int tid = threadIdx.x;
    const int bid = blockIdx.x;
    const int nid = ((bid & 7) << 9) + (bid >> 3);
    const int bh  = nid >> 6;
    const int t0  = (nid & 63) << 4;
    const int b   = bh >> 4, h = bh & 15;

    if (tid < 264) {
        int row, ch; const float* bias; u16* dst; bool act = true;
        if (tid < 128)      { row = tid >> 3;        ch = tid & 7; bias = rwb; dst = &qws[row * 72 + ch * 8]; }
        else if (tid < 256) { row = (tid - 128) >> 3; ch = tid & 7; bias = rrb; dst = &qrs[row * 72 + ch * 8]; }
        else if (MODE == 1) { row = 16;              ch = tid - 256; bias = rrb; dst = &qrs[16 * 72 + ch * 8]; }
        else act = false;
        if (act) {
            int trow = t0 + row; if (trow > 1023) trow = 1023;
            short8 qv = *(const short8*)(qsrc + b * qsb + (long long)trow * qld + h * 64 + ch * 8);
            const float* bp = bias + h * 64 + ch * 8;
            f4 b0 = *(const f4*)bp, b1 = *(const f4*)(bp + 4);
            short8 o;
            o[0] = (short)f2b((b2f((u16)qv[0]) + b0.x) * 0.125f);
            o[1] = (short)f2b((b2f((u16)qv[1]) + b0.y) * 0.125f);
            o[2] = (short)f2b((b2f((u16)qv[2]) + b0.z) * 0.125f);
            o[3] = (short)f2b((b2f((u16)qv[3]) + b0.w) * 0.125f);
            o[4] = (short)f2b((b2f((u16)qv[4]) + b1.x) * 0.125f);
            o[5] = (short)f2b((b2f((u16)qv[5]) + b1.y) * 0.125f);
            o[6] = (short)f2b((b2f((u16)qv[6]) + b1.z) * 0.125f);
            o[7] = (short)f2b((b2f((u16)qv[7]) + b1.w) * 0.125f);
            *(short8*)dst = o;
        }
    }
    __syncthreads();

    const int w = tid >> 6, lane = tid & 63;
    const int lc = lane & 15, g = lane >> 4, lk = g << 3;
    const int t = t0 + lc;

    const short8 bq0 = *(const short8*)&qws[lc * 72 + lk];
    const short8 bq1 = *(const short8*)&qws[lc * 72 + 32 + lk];
    const short8 br0 = *(const short8*)&qrs[lc * 72 + lk];
    const short8 br1 = *(const short8*)&qrs[lc * 72 + 32 + lk];
    short8 bs0 = {}, bs1 = {};
    if (MODE == 1) {
        bs0 = *(const short8*)&qrs[(lc + 1) * 72 + lk];
        bs1 = *(const short8*)&qrs[(lc + 1) * 72 + 32 + lk];
    }

    // ---- A0: BD~ pre-shifted write-only; 2-deep batched R-gathers
    #pragma unroll
    for (int Bb = 0; Bb < NI; Bb += 2) {
        short8 R0[2], R1[2];
        #pragma unroll
        for (int u = 0; u < 2; ++u) {
            const int ut = w + (Bb + u) * 8;
            const int u0 = ut << 4;
            const bool nd = (u0 + t0 + 30 >= 1023) || (MODE == 1 && u0 + t0 <= 1021);
            if (nd) {
                const u16* rg = rr + (long long)(u0 + lc) * 2048 + h * 64;
                R0[u] = *(const short8*)(rg + lk);
                R1[u] = *(const short8*)(rg + 32 + lk);
            }
        }
        #pragma unroll
        for (int u = 0; u < 2; ++u) {
            const int ut = w + (Bb + u) * 8;
            const int u0 = ut << 4;
            const bool need1 = (u0 + t0 + 30 >= 1023);
            const bool need2 = (MODE == 1) && (u0 + t0 <= 1021);
            if (need1) {
                f4 acc = {};
                acc = __builtin_amdgcn_mfma_f32_16x16x32_bf16(R0[u], br0, acc, 0, 0, 0);
                acc = __builtin_amdgcn_mfma_f32_16x16x32_bf16(R1[u], br1, acc, 0, 0, 0);
                #pragma unroll
                for (int i = 0; i < 4; ++i) {
                    const int j = u0 + 4 * g + i + t - 1023;
                    if (j >= 0) e[lc * LE + j] = f2b(acc[i]);
                }
            }
            if (MODE == 1 && need2) {
                f4 acc = {};
                acc = __builtin_amdgcn_mfma_f32_16x16x32_bf16(R0[u], bs0, acc, 0, 0, 0);
                acc = __builtin_amdgcn_mfma_f32_16x16x32_bf16(R1[u], bs1, acc, 0, 0, 0);
                #pragma unroll
                for (int i = 0; i < 4; ++i) {
                    const int j = u0 + 4 * g + i + t + 2;
                    if (j < KK) e[lc * LE + j] = f2b(acc[i]);
                }
            }
        }
    }
    __syncthreads();

    // ---- A1: AC + BD-add + exp + row-sum; pipelined 4-deep batched K-gathers
    float sum = 0.f;
    const int limit = t + 1024;
    const int jvt = (MODE == 0) ? ((t0 + 1039) >> 4) : (NT - 1);
    {
        short8 K0a[4], K0b[4], K1c[4];
        auto ldK0 = [&](short8* dst, int B2) {
            #pragma unroll
            for (int u = 0; u < 4; ++u) {
                const int jt = w + (B2 * 4 + u) * 8;
                if (MODE != 0 || jt <= jvt) {
                    const u16* kg = kb + (long long)(b * KK + (jt << 4) + lc) * kld + h * 64;
                    dst[u] = *(const short8*)(kg + lk);
                }
            }
        };
        ldK0(K0a, 0);
        #pragma unroll
        for (int B2 = 0; B2 < NB; ++B2) {
            short8* K0c = (B2 & 1) ? K0b : K0a;
            short8* K0n = (B2 & 1) ? K0a : K0b;
            #pragma unroll
            for (int u = 0; u < 4; ++u) {
                const int jt = w + (B2 * 4 + u) * 8;
                if (MODE != 0 || jt <= jvt) {
                    const u16* kg = kb + (long long)(b * KK + (jt << 4) + lc) * kld + h * 64;
                    K1c[u] = *(const short8*)(kg + 32 + lk);
                }
            }
            if (B2 + 1 < NB) ldK0(K0n, B2 + 1);
            __builtin_amdgcn_s_setprio(1);
            #pragma unroll
            for (int u = 0; u < 4; ++u) {
                const int jt = w + (B2 * 4 + u) * 8;
                const int jme = (jt << 4) + 4 * g;
                if (MODE == 0 && jt > jvt) {
                    u16x4 zz = {0, 0, 0, 0};
                    *(u16x4*)&e[lc * LE + jme] = zz;
                } else {
                    f4 acc = {};
                    acc = __builtin_amdgcn_mfma_f32_16x16x32_bf16(K0c[u], bq0, acc, 0, 0, 0);
                    acc = __builtin_amdgcn_mfma_f32_16x16x32_bf16(K1c[u], bq1, acc, 0, 0, 0);
                    u16x4 bd4 = *(const u16x4*)&e[lc * LE + jme];
                    u16x4 st;
                    #pragma unroll
                    for (int i = 0; i < 4; ++i) {
                        const int j = jme + i;
                        float bd = b2f(bd4[i]);
                        if (MODE == 1 && j == t + 1) bd = 0.f;
                        float ev = __expf(acc[i] + bd);
                        if (MODE == 0 && j > limit) ev = 0.f;
                        sum += ev;
                        st[i] = f2b(ev);
                    }
                    *(u16x4*)&e[lc * LE + jme] = st;
                }
            }
            __builtin_amdgcn_s_setprio(0);
        }
    }
    sum += __shfl_xor(sum, 16);
    sum += __shfl_xor(sum, 32);
    if (g == 0) psum[w][lc] = sum;
    __syncthreads();

    if (w >= 4) {
        const int r = (tid >> 4) & 15;
        const int q = tid & 15;
        float s = 0.f;
        #pragma unroll
        for (int w2 = 0; w2 < 8; ++w2) s += psum[w2][r];
        const float inv = 1.f / s;
        float* pr = probs + ((long long)bh * 1024 + t0 + r) * KK;
        #pragma unroll 4
        for (int i2 = 0; i2 < KK / 128; ++i2) {
            const int j0 = q * 8 + i2 * 128;
            u16x4 e0 = *(const u16x4*)&e[r * LE + j0];
            u16x4 e1 = *(const u16x4*)&e[r * LE + j0 + 4];
            f4 p0, p1;
            p0.x = b2f(e0.x) * inv; p0.y = b2f(e0.y) * inv;
            p0.z = b2f(e0.z) * inv; p0.w = b2f(e0.w) * inv;
            p1.x = b2f(e1.x) * inv; p1.y = b2f(e1.y) * inv;
            p1.z = b2f(e1.z) * inv; p1.w = b2f(e1.w) * inv;
            __builtin_nontemporal_store(p0, (f4*)(pr + j0));
            __builtin_nontemporal_store(p1, (f4*)(pr + j0 + 4));
        }
    } else {
        const int db = w << 4;
        const u16* vrow = vt + ((long long)(bh * 64 + db + lc)) * KK + lk;
        int kcend = KK / 32;
        if (MODE == 0) {
            const int ke = (t0 + 1071) >> 5;
            if (ke < kcend) kcend = ke;
        }
        f4 acc = {};
        __builtin_amdgcn_s_setprio(1);
        #pragma unroll 2
        for (int kc = 0; kc < kcend; ++kc) {
            short8 a = *(const short8*)&e[lc * LE + kc * 32 + lk];
            short8 bv = *(const short8*)(vrow + kc * 32);
            acc = __builtin_amdgcn_mfma_f32_16x16x32_bf16(a, bv, acc, 0, 0, 0);
        }
        __builtin_amdgcn_s_setprio(0);
        #pragma unroll
        for (int i = 0; i < 4; ++i) {
            const int trow = g * 4 + i;
            float s = 0.f;
            #pragma unroll
            for (int w2 = 0; w2 < 8; ++w2) s += psum[w2][trow];
            ob[((long long)(b * 1024 + t0 + trow)) * 1024 + h * 64 + db + lc] = f2b(acc[i] / s);
        }
    }
}

// ---------------------------------------------------------------------------
__global__ void prep0(const float* __restrict__ mem, const float* __restrict__ tgt,
                      const float* __restrict__ src, const float* __restrict__ pos,
                      float* __restrict__ nm, u16* __restrict__ cat,
                      u16* __restrict__ srcb, u16* __restrict__ posb)
{
    const int bid = blockIdx.x;
    const int tid = threadIdx.x;
    if (bid < 8192) {
        long long i = (long long)bid * 256 + tid;
        long long b = i >> 19;
        int rem = (int)(i & 524287);
        int r = rem >> 8, c4 = rem & 255;
        const float* sp = (r < 1024) ? (mem + ((b << 10) + r) * 1024 + c4 * 4)
                                     : (tgt + ((b << 10) + (r - 1024)) * 1024 + c4 * 4);
        f4 v = *(const f4*)sp;
        __builtin_nontemporal_store(v, (f4*)(nm + i * 4));
        u16x4 o; o.x = f2b(v.x); o.y = f2b(v.y); o.z = f2b(v.z); o.w = f2b(v.w);
        *(u16x4*)(cat + i * 4) = o;
    } else if (bid < 12288) {
        long long i = (long long)(bid - 8192) * 256 + tid;
        f4 v = *(const f4*)(src + i * 4);
        u16x4 o; o.x = f2b(v.x); o.y = f2b(v.y); o.z = f2b(v.z); o.w = f2b(v.w);
        *(u16x4*)(srcb + i * 4) = o;
    } else {
        long long i = (long long)(bid - 12288) * 256 + tid;
        f4 v = *(const f4*)(pos + i * 4);
        u16x4 o; o.x = f2b(v.x); o.y = f2b(v.y); o.z = f2b(v.z); o.w = f2b(v.w);
        *(u16x4*)(posb + i * 4) = o;
    }
}

struct TWS { const float* s; u16* d; int sld, dld; };
struct TW18 { TWS t[18]; };
__global__ void transpose_w18(TW18 p)
{
    __shared__ float tile[32][33];
    const TWS ts = p.t[blockIdx.z];
    int c0 = blockIdx.x * 32, r0 = blockIdx.y * 32;
    int tx = threadIdx.x, ty = threadIdx.y;
    tile[ty][tx] = ts.s[(long long)(r0 + ty) * ts.sld + c0 + tx];
    __syncthreads();
    ts.d[(long long)(c0 + ty) * ts.dld + r0 + tx] = f2b(tile[tx][ty]);
}

// out = LN(x + h1 + h2? + hbias?) * g + bl ; obf==nullptr -> NT final store.
__global__ __launch_bounds__(256) void ln_res(const float* __restrict__ x,
                                              const float* __restrict__ h1,
                                              const float* __restrict__ h2,
                                              const float* __restrict__ hbias,
                                              const float* __restrict__ g, const float* __restrict__ bl,
                                              float* __restrict__ o32, u16* __restrict__ obf)
{
    const long long row = blockIdx.x;
    const int tid = threadIdx.x;
    const long long base = row * 1024 + tid * 4;
    f4 xa = *(const f4*)(x + base);
    f4 ha = *(const f4*)(h1 + base);
    f4 hb = {0.f, 0.f, 0.f, 0.f};
    if (h2) hb = *(const f4*)(h2 + base);
    f4 hc = {0.f, 0.f, 0.f, 0.f};
    if (hbias) hc = *(const f4*)(hbias + tid * 4);
    float v0 = xa.x + ha.x + hb.x + hc.x, v1 = xa.y + ha.y + hb.y + hc.y;
    float v2 = xa.z + ha.z + hb.z + hc.z, v3 = xa.w + ha.w + hb.w + hc.w;
    float lsum = v0 + v1 + v2 + v3;
    float lsq = v0 * v0 + v1 * v1 + v2 * v2 + v3 * v3;
    #pragma unroll
    for (int o2 = 32; o2; o2 >>= 1) { lsum += __shfl_xor(lsum, o2); lsq += __shfl_xor(lsq, o2); }
    __shared__ float r1[4], r2[4];
    int w = tid >> 6, lane = tid & 63;
    if (lane == 0) { r1[w] = lsum; r2[w] = lsq; }
    __syncthreads();
    lsum = r1[0] + r1[1] + r1[2] + r1[3];
    lsq  = r2[0] + r2[1] + r2[2] + r2[3];
    const float mu = lsum * 0.0009765625f;
    const float var = lsq * 0.0009765625f - mu * mu;
    const float rsd = rsqrtf(var + 1e-5f);
    const int c = tid * 4;
    f4 gv = *(const f4*)(g + c);
    f4 bv = *(const f4*)(bl + c);
    f4 y;
    y.x = (v0 - mu) * rsd * gv.x + bv.x;
    y.y = (v1 - mu) * rsd * gv.y + bv.y;
    y.z = (v2 - mu) * rsd * gv.z + bv.z;
    y.w = (v3 - mu) * rsd * gv.w + bv.w;
    if (obf) {
        *(f4*)(o32 + base) = y;
        u16x4 u; u.x = f2b(y.x); u.y = f2b(y.y); u.z = f2b(y.z); u.w = f2b(y.w);
        *(u16x4*)(obf + base) = u;
    } else {
        __builtin_nontemporal_store(y, (f4*)(o32 + base));
    }
}

// ---------------------------------------------------------------------------
extern "C" void kernel_launch(void* const* d_in, const int* in_sizes, int n_in,
                              void* d_out, int out_size, void* d_ws, size_t ws_size,
                              hipStream_t stream)
{
    (void)in_sizes; (void)n_in; (void)out_size;
    const float* src  = (const float*)d_in[0];
    const float* tgt  = (const float*)d_in[1];
    const float* mem  = (const float*)d_in[2];
    const float* pos  = (const float*)d_in[3];
    const float* rwb  = (const float*)d_in[4];
    const float* rrb  = (const float*)d_in[5];
    const float* Wq1  = (const float*)d_in[6];
    const float* Wk1  = (const float*)d_in[7];
    const float* Wv1  = (const float*)d_in[8];
    const float* Wr1  = (const float*)d_in[9];
    const float* Wo1  = (const float*)d_in[10];
    const float* ln1g = (const float*)d_in[11];
    const float* ln1b = (const float*)d_in[12];
    const float* Wq2  = (const float*)d_in[13];
    const float* Wk2  = (const float*)d_in[14];
    const float* Wv2  = (const float*)d_in[15];
    const float* Wr2  = (const float*)d_in[16];
    const float* Wo2  = (const float*)d_in[17];
    const float* ln2g = (const float*)d_in[18];
    const float* ln2b = (const float*)d_in[19];
    const float* Wf1  = (const float*)d_in[20];
    const float* bf1  = (const float*)d_in[21];
    const float* Wf2  = (const float*)d_in[22];
    const float* bf2  = (const float*)d_in[23];
    const float* ln3g = (const float*)d_in[24];
    const float* ln3b = (const float*)d_in[25];

    float* outp   = (float*)d_out;            // [4,1024,1024]
    float* newmem = outp + 4194304;           // [4,2048,1024]
    float* selfP  = outp + 12582912;          // [4,16,1024,2048]
    float* interP = outp + 146800640;         // [4,16,1024,1024]

    char* ws = (char*)d_ws;
    size_t off = 0;
    auto alloc = [&](size_t bytes) -> void* {
        void* p = ws + off;
        off = (off + bytes + 255) & ~(size_t)255;
        return p;
    };
    u16*   src_bf  = (u16*)alloc(8u << 20);
    u16*   cat_bf  = (u16*)alloc(16u << 20);
    u16*   pos_bf  = (u16*)alloc(4u << 20);
    u16*   W1t    = (u16*)alloc(6u << 20);
    u16*   Wr12t  = (u16*)alloc(4u << 20);
    u16*   W2t    = (u16*)alloc(4u << 20);
    u16*   Wq2t   = (u16*)alloc(2u << 20);
    u16*   Wo1t   = (u16*)alloc(2u << 20);
    u16*   Wo2t   = (u16*)alloc(2u << 20);
    u16*   Wf1t   = (u16*)alloc(8u << 20);
    u16*   Wf2t   = (u16*)alloc(8u << 20);
    u16*   K1b    = (u16*)alloc(18u << 20);
    u16*   qb1    = (u16*)alloc(8u << 20);
    u16*   P2k    = (u16*)alloc(8u << 20);
    u16*   R12    = (u16*)alloc(8u << 20);
    u16*   qb2    = (u16*)alloc(8u << 20);
    u16*   vtb    = (u16*)alloc(16u << 20);
    u16*   ob     = (u16*)alloc(8u << 20);
    float* projb  = (float*)alloc(16u << 20);
    float* out1_32 = (float*)alloc(16u << 20);
    u16*   out1_bf = (u16*)alloc(8u << 20);
    float* out2_32 = (float*)alloc(16u << 20);
    u16*   out2_bf = (u16*)alloc(8u << 20);
    u16*   hb     = (u16*)alloc(32u << 20);
    if (off > ws_size) return;

    dim3 tb(32, 32);

    // ---- phase 0
    prep0<<<14336, 256, 0, stream>>>(mem, tgt, src, pos, newmem, cat_bf, src_bf, pos_bf);
    TW18 tw;
    tw.t[0] = {Wq1, W1t, 1024, 1024};
    tw.t[1] = {Wk1, W1t + 1048576, 1024, 1024};
    tw.t[2] = {Wv1, W1t + 2097152, 1024, 1024};
    tw.t[3] = {Wr1, Wr12t, 1024, 1024};
    tw.t[4] = {Wr2, Wr12t + 1048576, 1024, 1024};
    tw.t[5] = {Wk2, W2t, 1024, 1024};
    tw.t[6] = {Wv2, W2t + 1048576, 1024, 1024};
    tw.t[7] = {Wq2, Wq2t, 1024, 1024};
    tw.t[8] = {Wo1, Wo1t, 1024, 1024};
    tw.t[9] = {Wo2, Wo2t, 1024, 1024};
    for (int zz = 0; zz < 4; ++zz) {
        tw.t[10 + zz] = {Wf1 + zz * 1024, Wf1t + (long long)zz * 1048576, 4096, 1024};
        tw.t[14 + zz] = {Wf2 + (long long)zz * 1048576, Wf2t + zz * 1024, 1024, 4096};
    }
    transpose_w18<<<dim3(32, 32, 18), tb, 0, stream>>>(tw);

    // ---- layer 1: self relative attention (K=2048)
    // Merged K1 + V1^T: z=0 -> K1b (bf16, ld 1056); z=1 -> vtb (V^T, ld 2048)
    gemm_bt<4,4,3,0><<<dim3(8,64,2), 256, 0, stream>>>(cat_bf, W1t + 1048576, K1b, vtb, 2048,
        nullptr, 8192,1024,1024, 1024,1024,1056, 0,0, 0,1048576LL, 0,0, 1);
    gemm_bt<2,4,1,0><<<dim3(8,16,4), 256, 0, stream>>>(cat_bf + 1048576, W1t, qb1, nullptr, 0,
        nullptr, 1024,1024,1024, 1024,1024,1024, 0,2048LL*1024, 0,0, 0,1048576LL, 1);
    gemm_bt<2,4,1,0><<<dim3(16,32,1), 256, 0, stream>>>(pos_bf, Wr12t, R12, nullptr, 0,
        nullptr, 2048,2048,1024, 1024,1024,2048, 0,0,0,0,0,0, 1);
    fattn<2048,0><<<4096, 512, 0, stream>>>(qb1, 1024LL, 1048576LL,
        rwb, rrb, K1b, R12, vtb, selfP, ob, 1056);
    gemm_bt<2,4,0,0><<<dim3(8,64,1), 256, 0, stream>>>(ob, Wo1t, projb, nullptr, 0,
        nullptr, 4096,1024,1024, 1024,1024,1024, 0,0,0,0,0,0, 1);
    ln_res<<<4096, 256, 0, stream>>>(tgt, projb, nullptr, nullptr, ln1g, ln1b, out1_32, out1_bf);

    // ---- layer 2: cross relative attention (K=1024)
    {
        // Merged Q2/K2/V2^T: z=0: out1@Wq2 -> qb2; z=1: src@Wk2 -> P2k;
        // z=2: src@Wv2 -> vtb (V^T, ld 1024). batchH=2: z->(bb,hh)=(0,0),(0,1),(1,0)
        const long long dA = (long long)(src_bf - out1_bf);
        const long long dB = (long long)(W2t - Wq2t);
        const long long dB2 = (long long)((W2t + 1048576) - Wq2t);
        const long long dC = (long long)(P2k - qb2);
        gemm_bt<2,4,4,0><<<dim3(8,64,3), 256, 0, stream>>>(out1_bf, Wq2t, qb2, vtb, 1024,
            nullptr, 4096,1024,1024, 1024,1024,1024, dA,dA, dB,dB2, dC,0, 2);
    }
    fattn<1024,1><<<4096, 512, 0, stream>>>(qb2, 1024LL, 1048576LL,
        rwb, rrb, P2k, R12 + 1024LL * 2048 + 1024, vtb, interP, ob, 1024);
    gemm_bt<2,4,0,0><<<dim3(8,64,1), 256, 0, stream>>>(ob, Wo2t, projb, nullptr, 0,
        nullptr, 4096,1024,1024, 1024,1024,1024, 0,0,0,0,0,0, 1);
    ln_res<<<4096, 256, 0, stream>>>(out1_32, projb, nullptr, nullptr, ln2g, ln2b, out2_32, out2_bf);

    // ---- layer 3: FF
    gemm_bt<4,4,1,2><<<dim3(32,32,1), 256, 0, stream>>>(out2_bf, Wf1t, hb, nullptr, 0,
        bf1, 4096,4096,1024, 1024,1024,4096, 0,0,0,0,0,0, 1);
    gemm_bt<2,4,0,0><<<dim3(8,64,1), 256, 0, stream>>>(hb, Wf2t, projb, nullptr, 0,
        nullptr, 4096,1024,4096, 4096,4096,1024, 0,0,0,0,0,0, 1);
    ln_res<<<4096, 256, 0, stream>>>(out2_32, projb, nullptr, bf2, ln3g, ln3b, outp, nullptr);
}

// Round 17
// 875.264 us; speedup vs baseline: 1.0725x; 1.0019x over previous
//
#include <hip/hip_runtime.h>

typedef unsigned short u16;
typedef __attribute__((ext_vector_type(8))) short short8;
typedef __attribute__((ext_vector_type(4))) float f4;
typedef __attribute__((ext_vector_type(4))) unsigned short u16x4;

__device__ __forceinline__ float b2f(u16 u) {
    unsigned int x = ((unsigned int)u) << 16;
    return __builtin_bit_cast(float, x);
}
__device__ __forceinline__ u16 f2b(float f) {
    unsigned int u = __builtin_bit_cast(unsigned int, f);
    u += 0x7FFFu + ((u >> 16) & 1u);   // round-to-nearest-even
    return (u16)(u >> 16);
}

__device__ __forceinline__ void gl16(const void* g, void* l) {
    __builtin_amdgcn_global_load_lds(
        (const __attribute__((address_space(1))) void*)g,
        (__attribute__((address_space(3))) void*)l, 16, 0, 0);
}

// ---------------------------------------------------------------------------
// bf16 MFMA GEMM, global_load_lds staging + double-buffered LDS:
//   C[M,N] = A[M,K] @ Bt[N,K]^T  (+bias, +relu)
// Tile (FM*32)x(FN*32), BK=32, 4 waves (2x2).
// CBF: 0 f32-out, 1 bf16-out, 2 bf16 V^T-out,
//      3 z-switch {z=0: bf16->Cp ldc ; z=1: V^T->Cp2 ldc2},
//      4 z-switch {z<2: bf16->Cp+sCh*hh ; z=2: V^T->Cp2 ldc2}.
// EPI: 0 none, 1 +bias, 2 +bias+relu. Multi-source via batch strides.
// ---------------------------------------------------------------------------
template<int FM, int FN, int CBF, int EPI>
__global__ __launch_bounds__(256, 3)
void gemm_bt(const u16* __restrict__ Ap, const u16* __restrict__ Bp,
             void* __restrict__ Cp, void* __restrict__ Cp2, int ldc2,
             const float* __restrict__ bias,
             int M, int N, int K, int lda, int ldb, int ldc,
             long long sAh, long long sAb, long long sBh, long long sBb,
             long long sCh, long long sCb, int batchH)
{
    constexpr int BM = FM * 32;
    constexpr int BN = FN * 32;
    __shared__ __align__(16) u16 As[2][BM * 32];
    __shared__ __align__(16) u16 Bs[2][BN * 32];

    const int tid  = threadIdx.x;
    const int z    = blockIdx.z;
    const int bb   = z / batchH;
    const int hh   = z - bb * batchH;
    const int m0   = blockIdx.y * BM;
    const int n0   = blockIdx.x * BN;
    const int w    = tid >> 6;
    const int lane = tid & 63;
    const int wr   = w >> 1;
    const int wc   = w & 1;
    const int lrow = lane & 15;
    const int lk   = (lane >> 4) << 3;
    const int lrow4 = lane >> 2;
    const int lch   = lane & 3;

    const u16* Ag = Ap + sAb * bb + sAh * hh;
    const u16* Bg = Bp + sBb * bb + sBh * hh;

    f4 acc[FM][FN] = {};

    auto stage = [&](int buf, int kt) {
        const int kb = kt << 5;
        #pragma unroll
        for (int i = 0; i < BM / 64; ++i) {
            const int row0 = (w + i * 4) << 4;
            gl16(Ag + (long long)(m0 + row0 + lrow4) * lda + kb + (lch << 3),
                 &As[buf][row0 * 32]);
        }
        #pragma unroll
        for (int i = 0; i < BN / 64; ++i) {
            const int row0 = (w + i * 4) << 4;
            gl16(Bg + (long long)(n0 + row0 + lrow4) * ldb + kb + (lch << 3),
                 &Bs[buf][row0 * 32]);
        }
    };

    const int nKt = K >> 5;
    stage(0, 0);
    __syncthreads();
    int cur = 0;
    for (int kt = 0; kt < nKt; ++kt) {
        if (kt + 1 < nKt) stage(cur ^ 1, kt + 1);

        short8 af[FM], bv[FN];
        #pragma unroll
        for (int m = 0; m < FM; ++m)
            af[m] = *(const short8*)(&As[cur][(wr * FM * 16 + m * 16 + lrow) * 32 + lk]);
        #pragma unroll
        for (int n = 0; n < FN; ++n)
            bv[n] = *(const short8*)(&Bs[cur][(wc * FN * 16 + n * 16 + lrow) * 32 + lk]);
        #pragma unroll
        for (int m = 0; m < FM; ++m)
            #pragma unroll
            for (int n = 0; n < FN; ++n)
                acc[m][n] = __builtin_amdgcn_mfma_f32_16x16x32_bf16(af[m], bv[n], acc[m][n], 0, 0, 0);

        __syncthreads();
        cur ^= 1;
    }

    const int crow0 = m0 + wr * FM * 16 + ((lane >> 4) << 2);
    const int ccol0 = n0 + wc * FN * 16 + lrow;
    const bool vtpath = (CBF == 2) || (CBF == 3 && z == 1) || (CBF == 4 && z == 2);
    if (CBF == 0) {
        float* Cg = (float*)Cp + sCb * bb + sCh * hh;
        #pragma unroll
        for (int m = 0; m < FM; ++m) {
            #pragma unroll
            for (int n = 0; n < FN; ++n) {
                const int col = ccol0 + n * 16;
                float bvv = (EPI >= 1) ? bias[col] : 0.f;
                #pragma unroll
                for (int r = 0; r < 4; ++r) {
                    float vv = acc[m][n][r] + bvv;
                    if (EPI == 2) vv = fmaxf(vv, 0.f);
                    Cg[(long long)(crow0 + m * 16 + r) * ldc + col] = vv;
                }
            }
        }
    } else if (!vtpath) {
        u16* Cg = (u16*)Cp + sCb * bb + sCh * hh;
        #pragma unroll
        for (int m = 0; m < FM; ++m) {
            #pragma unroll
            for (int n = 0; n < FN; ++n) {
                const int col = ccol0 + n * 16;
                float bvv = (EPI >= 1) ? bias[col] : 0.f;
                #pragma unroll
                for (int r = 0; r < 4; ++r) {
                    float vv = acc[m][n][r] + bvv;
                    if (EPI == 2) vv = fmaxf(vv, 0.f);
                    Cg[(long long)(crow0 + m * 16 + r) * ldc + col] = f2b(vv);
                }
            }
        }
    } else {
        // V^T write: vt[(b*1024 + col)*ldv + j], b = row/ldv, j = row%ldv.
        const int ldv = (CBF == 2) ? ldc : ldc2;
        u16* Cg = (CBF == 2) ? (u16*)Cp : (u16*)Cp2;
        #pragma unroll
        for (int m = 0; m < FM; ++m) {
            const int row0 = crow0 + m * 16;
            const int b2 = row0 / ldv;
            const int j = row0 - b2 * ldv;
            #pragma unroll
            for (int n = 0; n < FN; ++n) {
                const int col = ccol0 + n * 16;
                u16x4 o;
                o.x = f2b(acc[m][n][0]); o.y = f2b(acc[m][n][1]);
                o.z = f2b(acc[m][n][2]); o.w = f2b(acc[m][n][3]);
                *(u16x4*)(Cg + ((long long)(b2 * 1024 + col)) * ldv + j) = o;
            }
        }
    }
}

// ---------------------------------------------------------------------------
// Fused attention v8: swapped-operand + wave-interleaved + XCD-swizzled grid
// + software-pipelined K gathers + setprio around MFMA clusters.
// 16 q-rows, 512 threads (8 waves), 1D grid 4096 (bijective XCD chunking).
// MODE 0: self causal (limit=t+1024), KK=2048. MODE 1: cross, KK=1024.
// ---------------------------------------------------------------------------
template<int KK, int MODE>
__global__ __launch_bounds__(512, 4)
void fattn(const u16* __restrict__ qsrc, long long qld, long long qsb,
           const float* __restrict__ rwb, const float* __restrict__ rrb,
           const u16* __restrict__ kb, const u16* __restrict__ rr,
           const u16* __restrict__ vt,
           float* __restrict__ probs, u16* __restrict__ ob, int kld)
{
    constexpr int LE = KK + 8;
    constexpr int NT = KK / 16;
    constexpr int NI = NT / 8;
    constexpr int NB = NI / 4;
    __shared__ __align__(16) u16 e[16 * LE];
    __shared__ __align__(16) u16 qws[16 * 72];
    __shared__ __align__(16) u16 qrs[17 * 72];
    __shared__ float psum[8][16];

    const int tid = threadIdx.x;
    const int bid = blockIdx.x;
    const int nid = ((bid & 7) << 9) + (bid >> 3);
    const int bh  = nid >> 6;
    const int t0  = (nid & 63) << 4;
    const int b   = bh >> 4, h = bh & 15;

    if (tid < 264) {
        int row, ch; const float* bias; u16* dst; bool act = true;
        if (tid < 128)      { row = tid >> 3;        ch = tid & 7; bias = rwb; dst = &qws[row * 72 + ch * 8]; }
        else if (tid < 256) { row = (tid - 128) >> 3; ch = tid & 7; bias = rrb; dst = &qrs[row * 72 + ch * 8]; }
        else if (MODE == 1) { row = 16;              ch = tid - 256; bias = rrb; dst = &qrs[16 * 72 + ch * 8]; }
        else act = false;
        if (act) {
            int trow = t0 + row; if (trow > 1023) trow = 1023;
            short8 qv = *(const short8*)(qsrc + b * qsb + (long long)trow * qld + h * 64 + ch * 8);
            const float* bp = bias + h * 64 + ch * 8;
            f4 b0 = *(const f4*)bp, b1 = *(const f4*)(bp + 4);
            short8 o;
            o[0] = (short)f2b((b2f((u16)qv[0]) + b0.x) * 0.125f);
            o[1] = (short)f2b((b2f((u16)qv[1]) + b0.y) * 0.125f);
            o[2] = (short)f2b((b2f((u16)qv[2]) + b0.z) * 0.125f);
            o[3] = (short)f2b((b2f((u16)qv[3]) + b0.w) * 0.125f);
            o[4] = (short)f2b((b2f((u16)qv[4]) + b1.x) * 0.125f);
            o[5] = (short)f2b((b2f((u16)qv[5]) + b1.y) * 0.125f);
            o[6] = (short)f2b((b2f((u16)qv[6]) + b1.z) * 0.125f);
            o[7] = (short)f2b((b2f((u16)qv[7]) + b1.w) * 0.125f);
            *(short8*)dst = o;
        }
    }
    __syncthreads();

    const int w = tid >> 6, lane = tid & 63;
    const int lc = lane & 15, g = lane >> 4, lk = g << 3;
    const int t = t0 + lc;

    const short8 bq0 = *(const short8*)&qws[lc * 72 + lk];
    const short8 bq1 = *(const short8*)&qws[lc * 72 + 32 + lk];
    const short8 br0 = *(const short8*)&qrs[lc * 72 + lk];
    const short8 br1 = *(const short8*)&qrs[lc * 72 + 32 + lk];
    short8 bs0 = {}, bs1 = {};
    if (MODE == 1) {
        bs0 = *(const short8*)&qrs[(lc + 1) * 72 + lk];
        bs1 = *(const short8*)&qrs[(lc + 1) * 72 + 32 + lk];
    }

    // ---- A0: BD~ pre-shifted write-only; 2-deep batched R-gathers
    #pragma unroll
    for (int Bb = 0; Bb < NI; Bb += 2) {
        short8 R0[2], R1[2];
        #pragma unroll
        for (int u = 0; u < 2; ++u) {
            const int ut = w + (Bb + u) * 8;
            const int u0 = ut << 4;
            const bool nd = (u0 + t0 + 30 >= 1023) || (MODE == 1 && u0 + t0 <= 1021);
            if (nd) {
                const u16* rg = rr + (long long)(u0 + lc) * 2048 + h * 64;
                R0[u] = *(const short8*)(rg + lk);
                R1[u] = *(const short8*)(rg + 32 + lk);
            }
        }
        #pragma unroll
        for (int u = 0; u < 2; ++u) {
            const int ut = w + (Bb + u) * 8;
            const int u0 = ut << 4;
            const bool need1 = (u0 + t0 + 30 >= 1023);
            const bool need2 = (MODE == 1) && (u0 + t0 <= 1021);
            if (need1) {
                f4 acc = {};
                acc = __builtin_amdgcn_mfma_f32_16x16x32_bf16(R0[u], br0, acc, 0, 0, 0);
                acc = __builtin_amdgcn_mfma_f32_16x16x32_bf16(R1[u], br1, acc, 0, 0, 0);
                #pragma unroll
                for (int i = 0; i < 4; ++i) {
                    const int j = u0 + 4 * g + i + t - 1023;
                    if (j >= 0) e[lc * LE + j] = f2b(acc[i]);
                }
            }
            if (MODE == 1 && need2) {
                f4 acc = {};
                acc = __builtin_amdgcn_mfma_f32_16x16x32_bf16(R0[u], bs0, acc, 0, 0, 0);
                acc = __builtin_amdgcn_mfma_f32_16x16x32_bf16(R1[u], bs1, acc, 0, 0, 0);
                #pragma unroll
                for (int i = 0; i < 4; ++i) {
                    const int j = u0 + 4 * g + i + t + 2;
                    if (j < KK) e[lc * LE + j] = f2b(acc[i]);
                }
            }
        }
    }
    __syncthreads();

    // ---- A1: AC + BD-add + exp + row-sum; pipelined 4-deep batched K-gathers
    float sum = 0.f;
    const int limit = t + 1024;
    const int jvt = (MODE == 0) ? ((t0 + 1039) >> 4) : (NT - 1);
    {
        short8 K0a[4], K0b[4], K1c[4];
        auto ldK0 = [&](short8* dst, int B2) {
            #pragma unroll
            for (int u = 0; u < 4; ++u) {
                const int jt = w + (B2 * 4 + u) * 8;
                if (MODE != 0 || jt <= jvt) {
                    const u16* kg = kb + (long long)(b * KK + (jt << 4) + lc) * kld + h * 64;
                    dst[u] = *(const short8*)(kg + lk);
                }
            }
        };
        ldK0(K0a, 0);
        #pragma unroll
        for (int B2 = 0; B2 < NB; ++B2) {
            short8* K0c = (B2 & 1) ? K0b : K0a;
            short8* K0n = (B2 & 1) ? K0a : K0b;
            #pragma unroll
            for (int u = 0; u < 4; ++u) {
                const int jt = w + (B2 * 4 + u) * 8;
                if (MODE != 0 || jt <= jvt) {
                    const u16* kg = kb + (long long)(b * KK + (jt << 4) + lc) * kld + h * 64;
                    K1c[u] = *(const short8*)(kg + 32 + lk);
                }
            }
            if (B2 + 1 < NB) ldK0(K0n, B2 + 1);
            __builtin_amdgcn_s_setprio(1);
            #pragma unroll
            for (int u = 0; u < 4; ++u) {
                const int jt = w + (B2 * 4 + u) * 8;
                const int jme = (jt << 4) + 4 * g;
                if (MODE == 0 && jt > jvt) {
                    u16x4 zz = {0, 0, 0, 0};
                    *(u16x4*)&e[lc * LE + jme] = zz;
                } else {
                    f4 acc = {};
                    acc = __builtin_amdgcn_mfma_f32_16x16x32_bf16(K0c[u], bq0, acc, 0, 0, 0);
                    acc = __builtin_amdgcn_mfma_f32_16x16x32_bf16(K1c[u], bq1, acc, 0, 0, 0);
                    u16x4 bd4 = *(const u16x4*)&e[lc * LE + jme];
                    u16x4 st;
                    #pragma unroll
                    for (int i = 0; i < 4; ++i) {
                        const int j = jme + i;
                        float bd = b2f(bd4[i]);
                        if (MODE == 1 && j == t + 1) bd = 0.f;
                        float ev = __expf(acc[i] + bd);
                        if (MODE == 0 && j > limit) ev = 0.f;
                        sum += ev;
                        st[i] = f2b(ev);
                    }
                    *(u16x4*)&e[lc * LE + jme] = st;
                }
            }
            __builtin_amdgcn_s_setprio(0);
        }
    }
    sum += __shfl_xor(sum, 16);
    sum += __shfl_xor(sum, 32);
    if (g == 0) psum[w][lc] = sum;
    __syncthreads();

    if (w >= 4) {
        const int r = (tid >> 4) & 15;
        const int q = tid & 15;
        float s = 0.f;
        #pragma unroll
        for (int w2 = 0; w2 < 8; ++w2) s += psum[w2][r];
        const float inv = 1.f / s;
        float* pr = probs + ((long long)bh * 1024 + t0 + r) * KK;
        #pragma unroll 4
        for (int i2 = 0; i2 < KK / 128; ++i2) {
            const int j0 = q * 8 + i2 * 128;
            u16x4 e0 = *(const u16x4*)&e[r * LE + j0];
            u16x4 e1 = *(const u16x4*)&e[r * LE + j0 + 4];
            f4 p0, p1;
            p0.x = b2f(e0.x) * inv; p0.y = b2f(e0.y) * inv;
            p0.z = b2f(e0.z) * inv; p0.w = b2f(e0.w) * inv;
            p1.x = b2f(e1.x) * inv; p1.y = b2f(e1.y) * inv;
            p1.z = b2f(e1.z) * inv; p1.w = b2f(e1.w) * inv;
            __builtin_nontemporal_store(p0, (f4*)(pr + j0));
            __builtin_nontemporal_store(p1, (f4*)(pr + j0 + 4));
        }
    } else {
        const int db = w << 4;
        const u16* vrow = vt + ((long long)(bh * 64 + db + lc)) * KK + lk;
        int kcend = KK / 32;
        if (MODE == 0) {
            const int ke = (t0 + 1071) >> 5;
            if (ke < kcend) kcend = ke;
        }
        f4 acc = {};
        __builtin_amdgcn_s_setprio(1);
        #pragma unroll 2
        for (int kc = 0; kc < kcend; ++kc) {
            short8 a = *(const short8*)&e[lc * LE + kc * 32 + lk];
            short8 bv = *(const short8*)(vrow + kc * 32);
            acc = __builtin_amdgcn_mfma_f32_16x16x32_bf16(a, bv, acc, 0, 0, 0);
        }
        __builtin_amdgcn_s_setprio(0);
        #pragma unroll
        for (int i = 0; i < 4; ++i) {
            const int trow = g * 4 + i;
            float s = 0.f;
            #pragma unroll
            for (int w2 = 0; w2 < 8; ++w2) s += psum[w2][trow];
            ob[((long long)(b * 1024 + t0 + trow)) * 1024 + h * 64 + db + lc] = f2b(acc[i] / s);
        }
    }
}

// ---------------------------------------------------------------------------
__global__ void prep0(const float* __restrict__ mem, const float* __restrict__ tgt,
                      const float* __restrict__ src, const float* __restrict__ pos,
                      float* __restrict__ nm, u16* __restrict__ cat,
                      u16* __restrict__ srcb, u16* __restrict__ posb)
{
    const int bid = blockIdx.x;
    const int tid = threadIdx.x;
    if (bid < 8192) {
        long long i = (long long)bid * 256 + tid;
        long long b = i >> 19;
        int rem = (int)(i & 524287);
        int r = rem >> 8, c4 = rem & 255;
        const float* sp = (r < 1024) ? (mem + ((b << 10) + r) * 1024 + c4 * 4)
                                     : (tgt + ((b << 10) + (r - 1024)) * 1024 + c4 * 4);
        f4 v = *(const f4*)sp;
        __builtin_nontemporal_store(v, (f4*)(nm + i * 4));
        u16x4 o; o.x = f2b(v.x); o.y = f2b(v.y); o.z = f2b(v.z); o.w = f2b(v.w);
        *(u16x4*)(cat + i * 4) = o;
    } else if (bid < 12288) {
        long long i = (long long)(bid - 8192) * 256 + tid;
        f4 v = *(const f4*)(src + i * 4);
        u16x4 o; o.x = f2b(v.x); o.y = f2b(v.y); o.z = f2b(v.z); o.w = f2b(v.w);
        *(u16x4*)(srcb + i * 4) = o;
    } else {
        long long i = (long long)(bid - 12288) * 256 + tid;
        f4 v = *(const f4*)(pos + i * 4);
        u16x4 o; o.x = f2b(v.x); o.y = f2b(v.y); o.z = f2b(v.z); o.w = f2b(v.w);
        *(u16x4*)(posb + i * 4) = o;
    }
}

struct TWS { const float* s; u16* d; int sld, dld; };
struct TW18 { TWS t[18]; };
__global__ void transpose_w18(TW18 p)
{
    __shared__ float tile[32][33];
    const TWS ts = p.t[blockIdx.z];
    int c0 = blockIdx.x * 32, r0 = blockIdx.y * 32;
    int tx = threadIdx.x, ty = threadIdx.y;
    tile[ty][tx] = ts.s[(long long)(r0 + ty) * ts.sld + c0 + tx];
    __syncthreads();
    ts.d[(long long)(c0 + ty) * ts.dld + r0 + tx] = f2b(tile[tx][ty]);
}

// out = LN(x + h1 + h2? + hbias?) * g + bl ; obf==nullptr -> NT final store.
__global__ __launch_bounds__(256) void ln_res(const float* __restrict__ x,
                                              const float* __restrict__ h1,
                                              const float* __restrict__ h2,
                                              const float* __restrict__ hbias,
                                              const float* __restrict__ g, const float* __restrict__ bl,
                                              float* __restrict__ o32, u16* __restrict__ obf)
{
    const long long row = blockIdx.x;
    const int tid = threadIdx.x;
    const long long base = row * 1024 + tid * 4;
    f4 xa = *(const f4*)(x + base);
    f4 ha = *(const f4*)(h1 + base);
    f4 hb = {0.f, 0.f, 0.f, 0.f};
    if (h2) hb = *(const f4*)(h2 + base);
    f4 hc = {0.f, 0.f, 0.f, 0.f};
    if (hbias) hc = *(const f4*)(hbias + tid * 4);
    float v0 = xa.x + ha.x + hb.x + hc.x, v1 = xa.y + ha.y + hb.y + hc.y;
    float v2 = xa.z + ha.z + hb.z + hc.z, v3 = xa.w + ha.w + hb.w + hc.w;
    float lsum = v0 + v1 + v2 + v3;
    float lsq = v0 * v0 + v1 * v1 + v2 * v2 + v3 * v3;
    #pragma unroll
    for (int o2 = 32; o2; o2 >>= 1) { lsum += __shfl_xor(lsum, o2); lsq += __shfl_xor(lsq, o2); }
    __shared__ float r1[4], r2[4];
    int w = tid >> 6, lane = tid & 63;
    if (lane == 0) { r1[w] = lsum; r2[w] = lsq; }
    __syncthreads();
    lsum = r1[0] + r1[1] + r1[2] + r1[3];
    lsq  = r2[0] + r2[1] + r2[2] + r2[3];
    const float mu = lsum * 0.0009765625f;
    const float var = lsq * 0.0009765625f - mu * mu;
    const float rsd = rsqrtf(var + 1e-5f);
    const int c = tid * 4;
    f4 gv = *(const f4*)(g + c);
    f4 bv = *(const f4*)(bl + c);
    f4 y;
    y.x = (v0 - mu) * rsd * gv.x + bv.x;
    y.y = (v1 - mu) * rsd * gv.y + bv.y;
    y.z = (v2 - mu) * rsd * gv.z + bv.z;
    y.w = (v3 - mu) * rsd * gv.w + bv.w;
    if (obf) {
        *(f4*)(o32 + base) = y;
        u16x4 u; u.x = f2b(y.x); u.y = f2b(y.y); u.z = f2b(y.z); u.w = f2b(y.w);
        *(u16x4*)(obf + base) = u;
    } else {
        __builtin_nontemporal_store(y, (f4*)(o32 + base));
    }
}

// ---------------------------------------------------------------------------
extern "C" void kernel_launch(void* const* d_in, const int* in_sizes, int n_in,
                              void* d_out, int out_size, void* d_ws, size_t ws_size,
                              hipStream_t stream)
{
    (void)in_sizes; (void)n_in; (void)out_size;
    const float* src  = (const float*)d_in[0];
    const float* tgt  = (const float*)d_in[1];
    const float* mem  = (const float*)d_in[2];
    const float* pos  = (const float*)d_in[3];
    const float* rwb  = (const float*)d_in[4];
    const float* rrb  = (const float*)d_in[5];
    const float* Wq1  = (const float*)d_in[6];
    const float* Wk1  = (const float*)d_in[7];
    const float* Wv1  = (const float*)d_in[8];
    const float* Wr1  = (const float*)d_in[9];
    const float* Wo1  = (const float*)d_in[10];
    const float* ln1g = (const float*)d_in[11];
    const float* ln1b = (const float*)d_in[12];
    const float* Wq2  = (const float*)d_in[13];
    const float* Wk2  = (const float*)d_in[14];
    const float* Wv2  = (const float*)d_in[15];
    const float* Wr2  = (const float*)d_in[16];
    const float* Wo2  = (const float*)d_in[17];
    const float* ln2g = (const float*)d_in[18];
    const float* ln2b = (const float*)d_in[19];
    const float* Wf1  = (const float*)d_in[20];
    const float* bf1  = (const float*)d_in[21];
    const float* Wf2  = (const float*)d_in[22];
    const float* bf2  = (const float*)d_in[23];
    const float* ln3g = (const float*)d_in[24];
    const float* ln3b = (const float*)d_in[25];

    float* outp   = (float*)d_out;            // [4,1024,1024]
    float* newmem = outp + 4194304;           // [4,2048,1024]
    float* selfP  = outp + 12582912;          // [4,16,1024,2048]
    float* interP = outp + 146800640;         // [4,16,1024,1024]

    char* ws = (char*)d_ws;
    size_t off = 0;
    auto alloc = [&](size_t bytes) -> void* {
        void* p = ws + off;
        off = (off + bytes + 255) & ~(size_t)255;
        return p;
    };
    u16*   src_bf  = (u16*)alloc(8u << 20);
    u16*   cat_bf  = (u16*)alloc(16u << 20);
    u16*   pos_bf  = (u16*)alloc(4u << 20);
    u16*   W1t    = (u16*)alloc(6u << 20);
    u16*   Wr12t  = (u16*)alloc(4u << 20);
    u16*   W2t    = (u16*)alloc(4u << 20);
    u16*   Wq2t   = (u16*)alloc(2u << 20);
    u16*   Wo1t   = (u16*)alloc(2u << 20);
    u16*   Wo2t   = (u16*)alloc(2u << 20);
    u16*   Wf1t   = (u16*)alloc(8u << 20);
    u16*   Wf2t   = (u16*)alloc(8u << 20);
    u16*   K1b    = (u16*)alloc(18u << 20);
    u16*   qb1    = (u16*)alloc(8u << 20);
    u16*   P2k    = (u16*)alloc(8u << 20);
    u16*   R12    = (u16*)alloc(8u << 20);
    u16*   qb2    = (u16*)alloc(8u << 20);
    u16*   vtb    = (u16*)alloc(16u << 20);
    u16*   ob     = (u16*)alloc(8u << 20);
    float* projb  = (float*)alloc(16u << 20);
    float* out1_32 = (float*)alloc(16u << 20);
    u16*   out1_bf = (u16*)alloc(8u << 20);
    float* out2_32 = (float*)alloc(16u << 20);
    u16*   out2_bf = (u16*)alloc(8u << 20);
    u16*   hb     = (u16*)alloc(32u << 20);
    if (off > ws_size) return;

    dim3 tb(32, 32);

    // ---- phase 0
    prep0<<<14336, 256, 0, stream>>>(mem, tgt, src, pos, newmem, cat_bf, src_bf, pos_bf);
    TW18 tw;
    tw.t[0] = {Wq1, W1t, 1024, 1024};
    tw.t[1] = {Wk1, W1t + 1048576, 1024, 1024};
    tw.t[2] = {Wv1, W1t + 2097152, 1024, 1024};
    tw.t[3] = {Wr1, Wr12t, 1024, 1024};
    tw.t[4] = {Wr2, Wr12t + 1048576, 1024, 1024};
    tw.t[5] = {Wk2, W2t, 1024, 1024};
    tw.t[6] = {Wv2, W2t + 1048576, 1024, 1024};
    tw.t[7] = {Wq2, Wq2t, 1024, 1024};
    tw.t[8] = {Wo1, Wo1t, 1024, 1024};
    tw.t[9] = {Wo2, Wo2t, 1024, 1024};
    for (int zz = 0; zz < 4; ++zz) {
        tw.t[10 + zz] = {Wf1 + zz * 1024, Wf1t + (long long)zz * 1048576, 4096, 1024};
        tw.t[14 + zz] = {Wf2 + (long long)zz * 1048576, Wf2t + zz * 1024, 1024, 4096};
    }
    transpose_w18<<<dim3(32, 32, 18), tb, 0, stream>>>(tw);

    // ---- layer 1: self relative attention (K=2048)
    // Merged K1 + V1^T: z=0 -> K1b (bf16, ld 1056); z=1 -> vtb (V^T, ld 2048)
    gemm_bt<4,4,3,0><<<dim3(8,64,2), 256, 0, stream>>>(cat_bf, W1t + 1048576, K1b, vtb, 2048,
        nullptr, 8192,1024,1024, 1024,1024,1056, 0,0, 0,1048576LL, 0,0, 1);
    gemm_bt<2,4,1,0><<<dim3(8,16,4), 256, 0, stream>>>(cat_bf + 1048576, W1t, qb1, nullptr, 0,
        nullptr, 1024,1024,1024, 1024,1024,1024, 0,2048LL*1024, 0,0, 0,1048576LL, 1);
    gemm_bt<2,4,1,0><<<dim3(16,32,1), 256, 0, stream>>>(pos_bf, Wr12t, R12, nullptr, 0,
        nullptr, 2048,2048,1024, 1024,1024,2048, 0,0,0,0,0,0, 1);
    fattn<2048,0><<<4096, 512, 0, stream>>>(qb1, 1024LL, 1048576LL,
        rwb, rrb, K1b, R12, vtb, selfP, ob, 1056);
    gemm_bt<2,4,0,0><<<dim3(8,64,1), 256, 0, stream>>>(ob, Wo1t, projb, nullptr, 0,
        nullptr, 4096,1024,1024, 1024,1024,1024, 0,0,0,0,0,0, 1);
    ln_res<<<4096, 256, 0, stream>>>(tgt, projb, nullptr, nullptr, ln1g, ln1b, out1_32, out1_bf);

    // ---- layer 2: cross relative attention (K=1024)
    {
        // Merged Q2/K2/V2^T: z=0: out1@Wq2 -> qb2; z=1: src@Wk2 -> P2k;
        // z=2: src@Wv2 -> vtb (V^T, ld 1024). batchH=2: z->(bb,hh)=(0,0),(0,1),(1,0)
        const long long dA = (long long)(src_bf - out1_bf);
        const long long dB = (long long)(W2t - Wq2t);
        const long long dB2 = (long long)((W2t + 1048576) - Wq2t);
        const long long dC = (long long)(P2k - qb2);
        gemm_bt<2,4,4,0><<<dim3(8,64,3), 256, 0, stream>>>(out1_bf, Wq2t, qb2, vtb, 1024,
            nullptr, 4096,1024,1024, 1024,1024,1024, dA,dA, dB,dB2, dC,0, 2);
    }
    fattn<1024,1><<<4096, 512, 0, stream>>>(qb2, 1024LL, 1048576LL,
        rwb, rrb, P2k, R12 + 1024LL * 2048 + 1024, vtb, interP, ob, 1024);
    gemm_bt<2,4,0,0><<<dim3(8,64,1), 256, 0, stream>>>(ob, Wo2t, projb, nullptr, 0,
        nullptr, 4096,1024,1024, 1024,1024,1024, 0,0,0,0,0,0, 1);
    ln_res<<<4096, 256, 0, stream>>>(out1_32, projb, nullptr, nullptr, ln2g, ln2b, out2_32, out2_bf);

    // ---- layer 3: FF
    gemm_bt<4,4,1,2><<<dim3(32,32,1), 256, 0, stream>>>(out2_bf, Wf1t, hb, nullptr, 0,
        bf1, 4096,4096,1024, 1024,1024,4096, 0,0,0,0,0,0, 1);
    gemm_bt<2,4,0,0><<<dim3(8,64,1), 256, 0, stream>>>(hb, Wf2t, projb, nullptr, 0,
        nullptr, 4096,1024,4096, 4096,4096,1024, 0,0,0,0,0,0, 1);
    ln_res<<<4096, 256, 0, stream>>>(out2_32, projb, nullptr, bf2, ln3g, ln3b, outp, nullptr);
}